// Round 4
// baseline (1502.149 us; speedup 1.0000x reference)
//
#include <hip/hip_runtime.h>
#include <math.h>

#define NB 16
#define NOBJ 128
#define NROLL 8

typedef float f2  __attribute__((ext_vector_type(2)));
typedef float f4v __attribute__((ext_vector_type(4)));

struct W {
  const float *rc0w,*rc0b,*rc1w,*rc1b,*rc2w,*rc2b;
  const float *at0w,*at0b,*at1w,*at1b,*at2w,*at2b;
  const float *af0w,*af0b,*af1w,*af1b,*af2w,*af2b;
  const float *o0w,*o0b,*o1w,*o1b;
  const float *sc0w,*sc0b,*sc1w,*sc1b;
};

// force a pointer into a VGPR so derived loads take the vector-memory path
// (L1-cached global_load_dwordx4) instead of scalar s_load (K$ thrash).
__device__ __forceinline__ const float* vgprize(const float* p){
  unsigned long long u = (unsigned long long)p;
  asm volatile("" : "+v"(u));
  return (const float*)u;
}

// branch-free tanh: 1 - 2/(e^{2x}+1).  inf/0 saturate to +-1 correctly.
__device__ __forceinline__ float fast_tanh(float x){
  float e = __expf(2.f * x);
  return 1.f - __fdividef(2.f, e + 1.f);
}

// ---------------------------------------------------------------------------
__global__ __launch_bounds__(128)
void encode_kernel(const float* __restrict__ x, const float* __restrict__ sew,
                   const float* __restrict__ seb, float* __restrict__ present,
                   float* __restrict__ S0)
{
  int bt = blockIdx.x;        // b*4 + t
  int o  = threadIdx.x;       // 0..127
  const float* xv = x + (size_t)(bt * NOBJ + o) * 4;
  float x0 = xv[0], x1 = xv[1], x2 = xv[2], x3 = xv[3];
  float* pr = present + (size_t)(bt * NOBJ + o) * 4;
  pr[0] = x0; pr[1] = x1; pr[2] = x2; pr[3] = x3;
  int t = bt & 3, b = bt >> 2;
  if (t == 3) {
    float* s = S0 + (size_t)(b * NOBJ + o) * 32;
    s[0] = x0; s[1] = x1; s[2] = x2; s[3] = x3;
    #pragma unroll
    for (int k = 4; k < 32; k++)
      s[k] = seb[k] + x0*sew[k] + x1*sew[32+k] + x2*sew[64+k] + x3*sew[96+k];
  }
}

// ---------------------------------------------------------------------------
__device__ void project_body(int tid, int bo, const float* __restrict__ s_sh,
                             float* __restrict__ h_sh, const W& w,
                             float* __restrict__ SD,
                             float* __restrict__ P1R, float* __restrict__ P1A,
                             float* __restrict__ P2R, float* __restrict__ P2A,
                             float* __restrict__ PX, float* __restrict__ PY)
{
  int b = bo >> 7, o = bo & 127;
  if (tid < 64) {
    float a1r = w.rc0b[tid], a2r = 0.f, a1a = w.at0b[tid], a2a = 0.f;
    #pragma unroll
    for (int c = 0; c < 32; c++) {
      float sv = s_sh[c];
      a1r += sv * w.rc0w[c*64 + tid];
      a2r += sv * w.rc0w[(32+c)*64 + tid];
      a1a += sv * w.at0w[c*64 + tid];
      a2a += sv * w.at0w[(32+c)*64 + tid];
    }
    P1R[(size_t)bo*64 + tid] = a1r;
    P1A[(size_t)bo*64 + tid] = a1a;
    P2R[(size_t)(b*64 + tid)*NOBJ + o] = a2r;  // transposed [b][k][j]
    P2A[(size_t)(b*64 + tid)*NOBJ + o] = a2a;
  }
  if (tid < 32) {
    float acc = w.sc0b[tid];
    #pragma unroll
    for (int c = 0; c < 32; c++) acc += s_sh[c] * w.sc0w[c*32 + tid];
    h_sh[tid] = fmaxf(acc, 0.f);
  }
  __syncthreads();
  if (tid < 32) {
    float acc = w.sc1b[tid] + h_sh[tid];
    #pragma unroll
    for (int c = 0; c < 32; c++) acc += h_sh[c] * w.sc1w[c*32 + tid];
    SD[(size_t)bo*32 + tid] = acc;
  }
  if (tid == 0) { PX[bo] = s_sh[0]; PY[bo] = s_sh[1]; }
}

__global__ __launch_bounds__(64)
void project_kernel(const float* __restrict__ S, W w,
                    float* SD, float* P1R, float* P1A,
                    float* P2R, float* P2A, float* PX, float* PY)
{
  __shared__ float s_sh[32], h_sh[32];
  int bo = blockIdx.x, tid = threadIdx.x;
  if (tid < 32) s_sh[tid] = S[(size_t)bo*32 + tid];
  __syncthreads();
  project_body(tid, bo, s_sh, h_sh, w, SD, P1R, P1A, P2R, P2A, PX, PY);
}

// ---------------------------------------------------------------------------
// one rollout step.  block = (b,i), 128 threads = one per j.
// Weights read from GLOBAL via forced-VGPR vector loads (L1-resident);
// GEMVs as chunked outer-products with f2 packed accumulators.
// ---------------------------------------------------------------------------
__global__ __launch_bounds__(128)
void step_kernel(const float* __restrict__ S_in,  const float* __restrict__ SD_in,
                 const float* __restrict__ P1R_in, const float* __restrict__ P1A_in,
                 const float* __restrict__ P2R_in, const float* __restrict__ P2A_in,
                 const float* __restrict__ PX_in,  const float* __restrict__ PY_in,
                 float* __restrict__ S_out, float* __restrict__ SD_out,
                 float* __restrict__ P1R_out, float* __restrict__ P1A_out,
                 float* __restrict__ P2R_out, float* __restrict__ P2A_out,
                 float* __restrict__ PX_out, float* __restrict__ PY_out,
                 W w, float* __restrict__ out_roll, int tstep)
{
  __shared__ __align__(16) float smem[896];
  float* geoA    = smem;          // 192  at0w rows 64..66
  float* geoR    = smem + 192;    // 192  rc0w rows 64..66
  float* bA      = smem + 384;    // 32   at1b
  float* bR      = smem + 416;    // 32   rc1b
  float* bC      = smem + 448;    // 32   rc2b
  float* wT2     = smem + 480;    // 32   at2w
  float* p1a_sh  = smem + 512;    // 64
  float* p1r_sh  = smem + 576;    // 64
  float* s_sh    = smem + 640;    // 32
  float* snew_sh = smem + 672;    // 32
  float* h_sh    = smem + 704;    // 32
  float* red     = smem + 736;    // 64 (2 waves x 32)
  float* v0_sh   = smem + 800;    // 32
  float* v1_sh   = smem + 832;    // 32
  float* v2_sh   = smem + 864;    // 32

  int bi = blockIdx.x;            // b*128 + i
  int b = bi >> 7, i = bi & 127;
  int tid = threadIdx.x;          // j
  int j = tid;

  // ---- stage small LDS data ----
  if (tid < 48)
    ((f4v*)geoA)[tid] = ((const f4v*)(w.at0w + 64*64))[tid];
  else if (tid < 96)
    ((f4v*)geoR)[tid-48] = ((const f4v*)(w.rc0w + 64*64))[tid-48];
  else {
    int t = tid - 96;  // 0..31
    bA[t]=w.at1b[t]; bR[t]=w.rc1b[t]; bC[t]=w.rc2b[t]; wT2[t]=w.at2w[t];
  }
  if (tid < 64) { p1a_sh[tid] = P1A_in[(size_t)bi*64 + tid];
                  p1r_sh[tid] = P1R_in[(size_t)bi*64 + tid]; }
  if (tid >= 96) s_sh[tid-96] = S_in[(size_t)bi*32 + (tid-96)];
  __syncthreads();

  const float* at1p = vgprize(w.at1w);
  const float* rc1p = vgprize(w.rc1w);
  const float* rc2p = vgprize(w.rc2w);

  float px_i = s_sh[0], py_i = s_sh[1];
  float px_j = PX_in[b*NOBJ + j], py_j = PY_in[b*NOBJ + j];
  float dx = px_i - px_j, dy = py_i - py_j;
  float dist = sqrtf(dx*dx + dy*dy + 1e-10f);

  const float* P2A_p = P2A_in + (size_t)b*64*NOBJ + j;
  const float* P2R_p = P2R_in + (size_t)b*64*NOBJ + j;

  // ---- attention path: 67->64 tanh (hoisted), chunked outer-product ----
  f2 acc[16];
  #pragma unroll
  for (int c = 0; c < 16; c++) acc[c] = *(const f2*)&bA[c*2];
  #pragma unroll
  for (int kc = 0; kc < 8; kc++) {
    float p2v[8];
    #pragma unroll
    for (int k = 0; k < 8; k++) p2v[k] = P2A_p[(kc*8+k)*NOBJ];
    #pragma unroll
    for (int k = 0; k < 8; k++) {
      int kk = kc*8 + k;
      float t = fast_tanh(p1a_sh[kk] + p2v[k]
                          + dist*geoA[kk] + dx*geoA[64+kk] + dy*geoA[128+kk]);
      #pragma unroll
      for (int cq = 0; cq < 8; cq++) {
        f4v wv = *(const f4v*)(at1p + kk*32 + cq*4);
        acc[cq*2]   += wv.xy * t;
        acc[cq*2+1] += wv.zw * t;
      }
    }
  }
  float att_acc = w.at2b[0];
  #pragma unroll
  for (int c = 0; c < 16; c++)
    att_acc += fast_tanh(acc[c].x)*wT2[c*2] + fast_tanh(acc[c].y)*wT2[c*2+1];
  float att = __expf(att_acc);
  if (j == i) att = 0.f;   // diag mask

  // ---- relation path: 67->64 relu (hoisted), chunked outer-product ----
  #pragma unroll
  for (int c = 0; c < 16; c++) acc[c] = *(const f2*)&bR[c*2];
  #pragma unroll
  for (int kc = 0; kc < 8; kc++) {
    float p2v[8];
    #pragma unroll
    for (int k = 0; k < 8; k++) p2v[k] = P2R_p[(kc*8+k)*NOBJ];
    #pragma unroll
    for (int k = 0; k < 8; k++) {
      int kk = kc*8 + k;
      float t = fmaxf(p1r_sh[kk] + p2v[k]
                      + dist*geoR[kk] + dx*geoR[64+kk] + dy*geoR[128+kk], 0.f);
      #pragma unroll
      for (int cq = 0; cq < 8; cq++) {
        f4v wv = *(const f4v*)(rc1p + kk*32 + cq*4);
        acc[cq*2]   += wv.xy * t;
        acc[cq*2+1] += wv.zw * t;
      }
    }
  }
  // rel2: 32->32 with +I residual folded via static indices
  f2 rel[16];
  #pragma unroll
  for (int c = 0; c < 16; c++) rel[c] = *(const f2*)&bC[c*2];
  #pragma unroll
  for (int k2 = 0; k2 < 32; k2++) {
    float r2v = fmaxf(acc[k2>>1][k2&1], 0.f);
    #pragma unroll
    for (int cq = 0; cq < 8; cq++) {
      f4v wv = *(const f4v*)(rc2p + k2*32 + cq*4);
      rel[cq*2]   += wv.xy * r2v;
      rel[cq*2+1] += wv.zw * r2v;
    }
    rel[k2>>1][k2&1] += r2v;   // +I residual (static index: k2 is unrolled)
  }
  #pragma unroll
  for (int c = 0; c < 16; c++) rel[c] *= att;

  // ---- reduce over 128 j-threads (wave butterfly + LDS combine) ----
  #pragma unroll
  for (int m = 1; m < 64; m <<= 1) {
    #pragma unroll
    for (int c = 0; c < 16; c++) {
      rel[c].x += __shfl_xor(rel[c].x, m);
      rel[c].y += __shfl_xor(rel[c].y, m);
    }
  }
  int wv_ = tid >> 6, lane = tid & 63;
  if (lane == 0) {
    #pragma unroll
    for (int c = 0; c < 16; c++) {
      red[wv_*32 + c*2]     = rel[c].x;
      red[wv_*32 + c*2 + 1] = rel[c].y;
    }
  }
  __syncthreads();

  // ---- per-object tail: 64 lanes, 2-way k-split + shfl_xor(32) ----
  int outc = tid & 31, half = (tid >> 5) & 1;
  if (tid < 32) v0_sh[tid] = SD_in[(size_t)bi*32 + tid] + red[tid] + red[32 + tid];
  __syncthreads();
  if (tid < 64) {                       // aff1 = tanh(dyn@af0+b)
    float a = 0.f;
    #pragma unroll
    for (int k = 0; k < 16; k++) a += v0_sh[half*16+k] * w.af0w[(half*16+k)*32 + outc];
    a += __shfl_xor(a, 32);
    if (half == 0) v1_sh[outc] = fast_tanh(a + w.af0b[outc]);
  }
  __syncthreads();
  if (tid < 64) {                       // aff2 = tanh(aff1@af1+b)+aff1
    float a = 0.f;
    #pragma unroll
    for (int k = 0; k < 16; k++) a += v1_sh[half*16+k] * w.af1w[(half*16+k)*32 + outc];
    a += __shfl_xor(a, 32);
    if (half == 0) v2_sh[outc] = fast_tanh(a + w.af1b[outc]) + v1_sh[outc];
  }
  __syncthreads();
  if (tid < 64) {                       // aff3 = aff2@af2+b
    float a = 0.f;
    #pragma unroll
    for (int k = 0; k < 16; k++) a += v2_sh[half*16+k] * w.af2w[(half*16+k)*32 + outc];
    a += __shfl_xor(a, 32);
    if (half == 0) v0_sh[outc] = a + w.af2b[outc];
  }
  __syncthreads();
  if (tid < 64) {                       // out1 = tanh([aff3,s]@o0+b)  K=64
    float a = 0.f;
    #pragma unroll
    for (int k = 0; k < 32; k++) {
      float src = half ? s_sh[k] : v0_sh[k];
      a += src * w.o0w[(half*32+k)*32 + outc];
    }
    a += __shfl_xor(a, 32);
    if (half == 0) v1_sh[outc] = fast_tanh(a + w.o0b[outc]);
  }
  __syncthreads();
  if (tid < 64) {                       // res = out1@o1+b+out1 (+s[:2])
    float a = 0.f;
    #pragma unroll
    for (int k = 0; k < 16; k++) a += v1_sh[half*16+k] * w.o1w[(half*16+k)*32 + outc];
    a += __shfl_xor(a, 32);
    if (half == 0) {
      a += w.o1b[outc] + v1_sh[outc];
      if (outc < 2) a += s_sh[outc];
      snew_sh[outc] = a;
      S_out[(size_t)bi*32 + outc] = a;
      if (outc < 4)
        out_roll[(size_t)((b*NROLL + tstep)*NOBJ + i)*4 + outc] = a;
    }
  }
  __syncthreads();

  // ---- fused projections of the NEW state for the next step ----
  project_body(tid, bi, snew_sh, h_sh, w,
               SD_out, P1R_out, P1A_out, P2R_out, P2A_out, PX_out, PY_out);
}

// ---------------------------------------------------------------------------
extern "C" void kernel_launch(void* const* d_in, const int* in_sizes, int n_in,
                              void* d_out, int out_size, void* d_ws, size_t ws_size,
                              hipStream_t stream)
{
  const float* x    = (const float*)d_in[0];
  const float* sew  = (const float*)d_in[1];
  const float* seb  = (const float*)d_in[2];
  W w;
  w.sc0w=(const float*)d_in[3];  w.sc0b=(const float*)d_in[4];
  w.sc1w=(const float*)d_in[5];  w.sc1b=(const float*)d_in[6];
  w.rc0w=(const float*)d_in[7];  w.rc0b=(const float*)d_in[8];
  w.rc1w=(const float*)d_in[9];  w.rc1b=(const float*)d_in[10];
  w.rc2w=(const float*)d_in[11]; w.rc2b=(const float*)d_in[12];
  w.at0w=(const float*)d_in[13]; w.at0b=(const float*)d_in[14];
  w.at1w=(const float*)d_in[15]; w.at1b=(const float*)d_in[16];
  w.at2w=(const float*)d_in[17]; w.at2b=(const float*)d_in[18];
  w.af0w=(const float*)d_in[19]; w.af0b=(const float*)d_in[20];
  w.af1w=(const float*)d_in[21]; w.af1b=(const float*)d_in[22];
  w.af2w=(const float*)d_in[23]; w.af2b=(const float*)d_in[24];
  w.o0w =(const float*)d_in[25]; w.o0b =(const float*)d_in[26];
  w.o1w =(const float*)d_in[27]; w.o1b =(const float*)d_in[28];

  float* out = (float*)d_out;
  float* out_roll    = out;                              // (16,8,128,4)
  float* out_present = out + NB*NROLL*NOBJ*4;            // (16,4,128,4)

  float* ws = (float*)d_ws;
  size_t off = 0;
  auto alloc = [&](size_t n){ float* p = ws + off; off += n; return p; };
  float* S[2]   = { alloc(NB*NOBJ*32), alloc(NB*NOBJ*32) };
  float* SD[2]  = { alloc(NB*NOBJ*32), alloc(NB*NOBJ*32) };
  float* P1R[2] = { alloc(NB*NOBJ*64), alloc(NB*NOBJ*64) };
  float* P1A[2] = { alloc(NB*NOBJ*64), alloc(NB*NOBJ*64) };
  float* P2R[2] = { alloc(NB*64*NOBJ), alloc(NB*64*NOBJ) };
  float* P2A[2] = { alloc(NB*64*NOBJ), alloc(NB*64*NOBJ) };
  float* PX[2]  = { alloc(NB*NOBJ),    alloc(NB*NOBJ) };
  float* PY[2]  = { alloc(NB*NOBJ),    alloc(NB*NOBJ) };
  (void)ws_size; (void)in_sizes; (void)n_in; (void)out_size;

  hipLaunchKernelGGL(encode_kernel, dim3(NB*4), dim3(NOBJ), 0, stream,
                     x, sew, seb, out_present, S[0]);
  hipLaunchKernelGGL(project_kernel, dim3(NB*NOBJ), dim3(64), 0, stream,
                     S[0], w, SD[0], P1R[0], P1A[0], P2R[0], P2A[0], PX[0], PY[0]);

  for (int t = 0; t < NROLL; t++) {
    int a = t & 1, oo = 1 - a;
    hipLaunchKernelGGL(step_kernel, dim3(NB*NOBJ), dim3(128), 0, stream,
                       S[a], SD[a], P1R[a], P1A[a], P2R[a], P2A[a], PX[a], PY[a],
                       S[oo], SD[oo], P1R[oo], P1A[oo], P2R[oo], P2A[oo], PX[oo], PY[oo],
                       w, out_roll, t);
  }
}

// Round 6
// 469.297 us; speedup vs baseline: 3.2008x; 3.2008x over previous
//
#include <hip/hip_runtime.h>
#include <math.h>

#define NB 16
#define NOBJ 128
#define NROLL 8

typedef short bfrag __attribute__((ext_vector_type(8)));   // 8 bf16 (4 VGPR)
typedef float f4t  __attribute__((ext_vector_type(4)));    // MFMA acc

struct W {
  const float *rc0w,*rc0b,*rc1w,*rc1b,*rc2w,*rc2b;
  const float *at0w,*at0b,*at1w,*at1b,*at2w,*at2b;
  const float *af0w,*af0b,*af1w,*af1b,*af2w,*af2b;
  const float *o0w,*o0b,*o1w,*o1b;
  const float *sc0w,*sc0b,*sc1w,*sc1b;
};

// branch-free tanh: 1 - 2/(e^{2x}+1); saturates correctly at +-inf.
__device__ __forceinline__ float fast_tanh(float x){
  float e = __expf(2.f * x);
  return 1.f - __fdividef(2.f, e + 1.f);
}

// fp32 -> bf16 round-to-nearest-even
__device__ __forceinline__ unsigned short f2bf(float f){
  unsigned u = __float_as_uint(f);
  u = u + 0x7fffu + ((u >> 16) & 1u);
  return (unsigned short)(u >> 16);
}

// ---------------------------------------------------------------------------
__global__ __launch_bounds__(128)
void encode_kernel(const float* __restrict__ x, const float* __restrict__ sew,
                   const float* __restrict__ seb, float* __restrict__ present,
                   float* __restrict__ S0)
{
  int bt = blockIdx.x;        // b*4 + t
  int o  = threadIdx.x;       // 0..127
  const float* xv = x + (size_t)(bt * NOBJ + o) * 4;
  float x0 = xv[0], x1 = xv[1], x2 = xv[2], x3 = xv[3];
  float* pr = present + (size_t)(bt * NOBJ + o) * 4;
  pr[0] = x0; pr[1] = x1; pr[2] = x2; pr[3] = x3;
  int t = bt & 3, b = bt >> 2;
  if (t == 3) {
    float* s = S0 + (size_t)(b * NOBJ + o) * 32;
    s[0] = x0; s[1] = x1; s[2] = x2; s[3] = x3;
    #pragma unroll
    for (int k = 4; k < 32; k++)
      s[k] = seb[k] + x0*sew[k] + x1*sew[32+k] + x2*sew[64+k] + x3*sew[96+k];
  }
}

// ---------------------------------------------------------------------------
// per-object projections: P1r/P1a (hoisted layer-1 i-halves), P2ar (j-halves,
// interleaved float2, transposed [b][k][j]), self_dyn, positions.
// ---------------------------------------------------------------------------
__device__ void project_body(int tid, int bo, const float* __restrict__ s_sh,
                             float* __restrict__ h_sh, const W& w,
                             float* __restrict__ SD,
                             float* __restrict__ P1R, float* __restrict__ P1A,
                             float* __restrict__ P2AR,
                             float* __restrict__ PX, float* __restrict__ PY)
{
  int b = bo >> 7, o = bo & 127;
  if (tid < 64) {
    float a1r = w.rc0b[tid], a2r = 0.f, a1a = w.at0b[tid], a2a = 0.f;
    #pragma unroll
    for (int c = 0; c < 32; c++) {
      float sv = s_sh[c];
      a1r += sv * w.rc0w[c*64 + tid];
      a2r += sv * w.rc0w[(32+c)*64 + tid];
      a1a += sv * w.at0w[c*64 + tid];
      a2a += sv * w.at0w[(32+c)*64 + tid];
    }
    P1R[(size_t)bo*64 + tid] = a1r;
    P1A[(size_t)bo*64 + tid] = a1a;
    float2 p; p.x = a2a; p.y = a2r;
    ((float2*)P2AR)[(size_t)(b*64 + tid)*NOBJ + o] = p;
  }
  if (tid < 32) {
    float acc = w.sc0b[tid];
    #pragma unroll
    for (int c = 0; c < 32; c++) acc += s_sh[c] * w.sc0w[c*32 + tid];
    h_sh[tid] = fmaxf(acc, 0.f);
  }
  __syncthreads();
  if (tid < 32) {
    float acc = w.sc1b[tid] + h_sh[tid];
    #pragma unroll
    for (int c = 0; c < 32; c++) acc += h_sh[c] * w.sc1w[c*32 + tid];
    SD[(size_t)bo*32 + tid] = acc;
  }
  if (tid == 0) { PX[bo] = s_sh[0]; PY[bo] = s_sh[1]; }
}

__global__ __launch_bounds__(64)
void project_kernel(const float* __restrict__ S, W w,
                    float* SD, float* P1R, float* P1A,
                    float* P2AR, float* PX, float* PY)
{
  __shared__ float s_sh[32], h_sh[32];
  int bo = blockIdx.x, tid = threadIdx.x;
  if (tid < 32) s_sh[tid] = S[(size_t)bo*32 + tid];
  __syncthreads();
  project_body(tid, bo, s_sh, h_sh, w, SD, P1R, P1A, P2AR, PX, PY);
}

// prep pass: compute 67->64 pre-acts for this thread's j, activation, bf16,
// write row j of the swizzled LDS tile (slot s lands at s^(j&7)).
#define PREP_PASS(P1PTR, GPTR, IS_TANH, USE_Y) do {                           \
  const float* p1_ = (P1PTR); const float* g_ = (GPTR);                       \
  _Pragma("unroll")                                                           \
  for (int s = 0; s < 8; s++){                                                \
    unsigned pw0, pw1, pw2, pw3;                                              \
    _Pragma("unroll")                                                         \
    for (int e2 = 0; e2 < 4; e2++){                                           \
      int k0 = s*8 + e2*2, k1 = k0+1;                                         \
      float2 pa0 = p2p[(size_t)k0*NOBJ];                                      \
      float2 pa1 = p2p[(size_t)k1*NOBJ];                                      \
      float x0 = (USE_Y) ? pa0.y : pa0.x;                                     \
      float x1 = (USE_Y) ? pa1.y : pa1.x;                                     \
      float pre0 = p1_[k0] + x0 + dist*g_[k0] + dx*g_[64+k0] + dy*g_[128+k0]; \
      float pre1 = p1_[k1] + x1 + dist*g_[k1] + dx*g_[64+k1] + dy*g_[128+k1]; \
      float a0 = (IS_TANH) ? fast_tanh(pre0) : fmaxf(pre0, 0.f);              \
      float a1 = (IS_TANH) ? fast_tanh(pre1) : fmaxf(pre1, 0.f);              \
      unsigned pp = (unsigned)f2bf(a0) | ((unsigned)f2bf(a1) << 16);          \
      if (e2 == 0) pw0 = pp; else if (e2 == 1) pw1 = pp;                      \
      else if (e2 == 2) pw2 = pp; else pw3 = pp;                              \
    }                                                                         \
    uint4 pk; pk.x = pw0; pk.y = pw1; pk.z = pw2; pk.w = pw3;                 \
    *((uint4*)((char*)smem + (j<<7) + ((s ^ (j&7))<<4))) = pk;                \
  }                                                                           \
} while(0)

// GEMM pass: [128x64] (LDS, bf16, swizzled) @ [64x32] (B-frags in regs).
// wave wv owns M-tiles wv*4..wv*4+3; A-frag: lane l = row (l&15), k-chunk l>>4.
#define GEMM_PASS(BF, COUT) do {                                              \
  _Pragma("unroll")                                                           \
  for (int mt = 0; mt < 4; mt++){                                             \
    int jr = (wv<<6) + (mt<<4) + c16;                                         \
    bfrag a0 = *((const bfrag*)((const char*)smem + (jr<<7) + (((qg  ) ^ (jr&7))<<4))); \
    bfrag a1 = *((const bfrag*)((const char*)smem + (jr<<7) + (((4+qg) ^ (jr&7))<<4))); \
    _Pragma("unroll")                                                         \
    for (int nt = 0; nt < 2; nt++){                                           \
      COUT[mt][nt] = __builtin_amdgcn_mfma_f32_16x16x32_bf16(a0, BF[nt][0], COUT[mt][nt], 0,0,0); \
      COUT[mt][nt] = __builtin_amdgcn_mfma_f32_16x16x32_bf16(a1, BF[nt][1], COUT[mt][nt], 0,0,0); \
    }                                                                         \
  }                                                                           \
} while(0)

// ---------------------------------------------------------------------------
// one rollout step.  block = (b,i), 128 threads (2 waves).
// ---------------------------------------------------------------------------
__global__ __launch_bounds__(128)
void step_kernel(const float* __restrict__ S_in,  const float* __restrict__ SD_in,
                 const float* __restrict__ P1R_in, const float* __restrict__ P1A_in,
                 const float* __restrict__ P2AR_in,
                 const float* __restrict__ PX_in,  const float* __restrict__ PY_in,
                 float* __restrict__ S_out, float* __restrict__ SD_out,
                 float* __restrict__ P1R_out, float* __restrict__ P1A_out,
                 float* __restrict__ P2AR_out,
                 float* __restrict__ PX_out, float* __restrict__ PY_out,
                 W w, float* __restrict__ out_roll, int tstep)
{
  __shared__ __align__(16) float smem[4352];   // [0,4096): 128x64 bf16 tile
  float* qbuf    = smem + 4096;  // 2 waves x (32 q + 1 A) = 66
  float* v0_sh   = smem + 4164;  // 32
  float* v1_sh   = smem + 4196;  // 32
  float* v2_sh   = smem + 4228;  // 32
  float* snew_sh = smem + 4260;  // 32
  float* h_sh    = smem + 4292;  // 32

  int bi = blockIdx.x;            // b*128 + i
  int b = bi >> 7, i = bi & 127;
  int tid = threadIdx.x;          // j
  int j = tid;
  int wv = tid >> 6, l = tid & 63;
  int c16 = l & 15, qg = l >> 4;  // MFMA lane coords

  // ---- B-fragments (weights), loaded once into registers ----
  bfrag bfA[2][2], bfR[2][2];
  #pragma unroll
  for (int nt = 0; nt < 2; nt++)
    #pragma unroll
    for (int kt = 0; kt < 2; kt++)
      #pragma unroll
      for (int e = 0; e < 8; e++) {
        int k = kt*32 + qg*8 + e;
        bfA[nt][kt][e] = (short)f2bf(w.at1w[k*32 + nt*16 + c16]);
        bfR[nt][kt][e] = (short)f2bf(w.rc1w[k*32 + nt*16 + c16]);
      }

  // ---- geometry (uniform i-state via scalar loads, per-j via vector) ----
  float px_i = S_in[(size_t)bi*32 + 0], py_i = S_in[(size_t)bi*32 + 1];
  float px_j = PX_in[b*NOBJ + j], py_j = PY_in[b*NOBJ + j];
  float dx = px_i - px_j, dy = py_i - py_j;
  float dist = sqrtf(dx*dx + dy*dy + 1e-10f);

  const float2* p2p = ((const float2*)P2AR_in) + (size_t)(b*64)*NOBJ + j;

  // ================= attention path =================
  PREP_PASS(P1A_in + (size_t)bi*64, w.at0w + 64*64, 1, 0);
  __syncthreads();
  f4t cA[4][2];
  #pragma unroll
  for (int mt = 0; mt < 4; mt++)
    #pragma unroll
    for (int nt = 0; nt < 2; nt++) cA[mt][nt] = (f4t){0.f,0.f,0.f,0.f};
  GEMM_PASS(bfA, cA);
  __syncthreads();   // tile reads done; epilogue is reg-only

  float attv[16];
  {
    float bA0 = w.at1b[c16], bA1 = w.at1b[16 + c16];
    float w20 = w.at2w[c16], w21 = w.at2w[16 + c16];
    float a2b = w.at2b[0];
    #pragma unroll
    for (int mt = 0; mt < 4; mt++)
      #pragma unroll
      for (int reg = 0; reg < 4; reg++) {
        float s = fast_tanh(cA[mt][0][reg] + bA0) * w20
                + fast_tanh(cA[mt][1][reg] + bA1) * w21;
        s += __shfl_xor(s, 1); s += __shfl_xor(s, 2);
        s += __shfl_xor(s, 4); s += __shfl_xor(s, 8);
        int jj = wv*64 + mt*16 + qg*4 + reg;
        attv[mt*4 + reg] = (jj == i) ? 0.f : __expf(s + a2b);
      }
  }

  // ================= relation path =================
  PREP_PASS(P1R_in + (size_t)bi*64, w.rc0w + 64*64, 0, 1);
  __syncthreads();
  f4t cR[4][2];
  #pragma unroll
  for (int mt = 0; mt < 4; mt++)
    #pragma unroll
    for (int nt = 0; nt < 2; nt++) cR[mt][nt] = (f4t){0.f,0.f,0.f,0.f};
  GEMM_PASS(bfR, cR);

  // epilogue: q = sum_j att_j * relu(r2pre_j), A = sum_j att_j
  {
    float bR0 = w.rc1b[c16], bR1 = w.rc1b[16 + c16];
    float q0 = 0.f, q1 = 0.f, Ap = 0.f;
    #pragma unroll
    for (int mt = 0; mt < 4; mt++)
      #pragma unroll
      for (int reg = 0; reg < 4; reg++) {
        float av = attv[mt*4 + reg]; Ap += av;
        q0 += av * fmaxf(cR[mt][0][reg] + bR0, 0.f);
        q1 += av * fmaxf(cR[mt][1][reg] + bR1, 0.f);
      }
    q0 += __shfl_xor(q0, 16); q0 += __shfl_xor(q0, 32);
    q1 += __shfl_xor(q1, 16); q1 += __shfl_xor(q1, 32);
    Ap += __shfl_xor(Ap, 16); Ap += __shfl_xor(Ap, 32);
    if (l < 16) { qbuf[wv*33 + l] = q0; qbuf[wv*33 + 16 + l] = q1; }
    if (l == 0) qbuf[wv*33 + 32] = Ap;
  }
  __syncthreads();

  // ---- per-object tail (32 threads) ----
  if (tid < 32) v2_sh[tid] = qbuf[tid] + qbuf[33 + tid];     // q combined
  __syncthreads();
  if (tid < 32) {                       // dyn = SD + q@rc2w + A*rc2b + q
    float A = qbuf[32] + qbuf[65];
    float acc = SD_in[(size_t)bi*32 + tid] + A * w.rc2b[tid] + v2_sh[tid];
    for (int k = 0; k < 32; k++) acc += v2_sh[k] * w.rc2w[k*32 + tid];
    v0_sh[tid] = acc;
  }
  __syncthreads();
  if (tid < 32) {                       // aff1
    float acc = w.af0b[tid];
    for (int k = 0; k < 32; k++) acc += v0_sh[k] * w.af0w[k*32 + tid];
    v1_sh[tid] = fast_tanh(acc);
  }
  __syncthreads();
  if (tid < 32) {                       // aff2
    float acc = w.af1b[tid];
    for (int k = 0; k < 32; k++) acc += v1_sh[k] * w.af1w[k*32 + tid];
    v2_sh[tid] = fast_tanh(acc) + v1_sh[tid];
  }
  __syncthreads();
  if (tid < 32) {                       // aff3
    float acc = w.af2b[tid];
    for (int k = 0; k < 32; k++) acc += v2_sh[k] * w.af2w[k*32 + tid];
    v0_sh[tid] = acc;
  }
  __syncthreads();
  if (tid < 32) {                       // out1 = tanh([aff3,s]@o0+b)
    float acc = w.o0b[tid];
    for (int k = 0; k < 32; k++) acc += v0_sh[k] * w.o0w[k*32 + tid];
    for (int k = 0; k < 32; k++) acc += S_in[(size_t)bi*32 + k] * w.o0w[(32+k)*32 + tid];
    v1_sh[tid] = fast_tanh(acc);
  }
  __syncthreads();
  if (tid < 32) {                       // res = out1@o1 + b + out1 (+s[:2])
    float acc = w.o1b[tid] + v1_sh[tid];
    for (int k = 0; k < 32; k++) acc += v1_sh[k] * w.o1w[k*32 + tid];
    if (tid < 2) acc += S_in[(size_t)bi*32 + tid];
    snew_sh[tid] = acc;
    S_out[(size_t)bi*32 + tid] = acc;
    if (tid < 4)
      out_roll[(size_t)((b*NROLL + tstep)*NOBJ + i)*4 + tid] = acc;
  }
  __syncthreads();

  // ---- fused projections of the NEW state for the next step ----
  project_body(tid, bi, snew_sh, h_sh, w,
               SD_out, P1R_out, P1A_out, P2AR_out, PX_out, PY_out);
}

// ---------------------------------------------------------------------------
extern "C" void kernel_launch(void* const* d_in, const int* in_sizes, int n_in,
                              void* d_out, int out_size, void* d_ws, size_t ws_size,
                              hipStream_t stream)
{
  const float* x    = (const float*)d_in[0];
  const float* sew  = (const float*)d_in[1];
  const float* seb  = (const float*)d_in[2];
  W w;
  w.sc0w=(const float*)d_in[3];  w.sc0b=(const float*)d_in[4];
  w.sc1w=(const float*)d_in[5];  w.sc1b=(const float*)d_in[6];
  w.rc0w=(const float*)d_in[7];  w.rc0b=(const float*)d_in[8];
  w.rc1w=(const float*)d_in[9];  w.rc1b=(const float*)d_in[10];
  w.rc2w=(const float*)d_in[11]; w.rc2b=(const float*)d_in[12];
  w.at0w=(const float*)d_in[13]; w.at0b=(const float*)d_in[14];
  w.at1w=(const float*)d_in[15]; w.at1b=(const float*)d_in[16];
  w.at2w=(const float*)d_in[17]; w.at2b=(const float*)d_in[18];
  w.af0w=(const float*)d_in[19]; w.af0b=(const float*)d_in[20];
  w.af1w=(const float*)d_in[21]; w.af1b=(const float*)d_in[22];
  w.af2w=(const float*)d_in[23]; w.af2b=(const float*)d_in[24];
  w.o0w =(const float*)d_in[25]; w.o0b =(const float*)d_in[26];
  w.o1w =(const float*)d_in[27]; w.o1b =(const float*)d_in[28];

  float* out = (float*)d_out;
  float* out_roll    = out;                              // (16,8,128,4)
  float* out_present = out + NB*NROLL*NOBJ*4;            // (16,4,128,4)

  float* ws = (float*)d_ws;
  size_t off = 0;
  auto alloc = [&](size_t n){ float* p = ws + off; off += n; return p; };
  float* S[2]    = { alloc(NB*NOBJ*32),   alloc(NB*NOBJ*32) };
  float* SD[2]   = { alloc(NB*NOBJ*32),   alloc(NB*NOBJ*32) };
  float* P1R[2]  = { alloc(NB*NOBJ*64),   alloc(NB*NOBJ*64) };
  float* P1A[2]  = { alloc(NB*NOBJ*64),   alloc(NB*NOBJ*64) };
  float* P2AR[2] = { alloc(NB*64*NOBJ*2), alloc(NB*64*NOBJ*2) };
  float* PX[2]   = { alloc(NB*NOBJ),      alloc(NB*NOBJ) };
  float* PY[2]   = { alloc(NB*NOBJ),      alloc(NB*NOBJ) };
  (void)ws_size; (void)in_sizes; (void)n_in; (void)out_size;

  hipLaunchKernelGGL(encode_kernel, dim3(NB*4), dim3(NOBJ), 0, stream,
                     x, sew, seb, out_present, S[0]);
  hipLaunchKernelGGL(project_kernel, dim3(NB*NOBJ), dim3(64), 0, stream,
                     S[0], w, SD[0], P1R[0], P1A[0], P2AR[0], PX[0], PY[0]);

  for (int t = 0; t < NROLL; t++) {
    int a = t & 1, oo = 1 - a;
    hipLaunchKernelGGL(step_kernel, dim3(NB*NOBJ), dim3(128), 0, stream,
                       S[a], SD[a], P1R[a], P1A[a], P2AR[a], PX[a], PY[a],
                       S[oo], SD[oo], P1R[oo], P1A[oo], P2AR[oo], PX[oo], PY[oo],
                       w, out_roll, t);
  }
}

// Round 8
// 405.577 us; speedup vs baseline: 3.7037x; 1.1571x over previous
//
#include <hip/hip_runtime.h>
#include <math.h>

#define NB 16
#define NOBJ 128
#define NROLL 8

typedef short bfrag __attribute__((ext_vector_type(8)));   // 8 bf16 (4 VGPR)
typedef float f4t  __attribute__((ext_vector_type(4)));    // MFMA acc

struct W {
  const float *rc0w,*rc0b,*rc1w,*rc1b,*rc2w,*rc2b;
  const float *at0w,*at0b,*at1w,*at1b,*at2w,*at2b;
  const float *af0w,*af0b,*af1w,*af1b,*af2w,*af2b;
  const float *o0w,*o0b,*o1w,*o1b;
  const float *sc0w,*sc0b,*sc1w,*sc1b;
};

// branch-free tanh: 1 - 2/(e^{2x}+1); saturates correctly at +-inf.
__device__ __forceinline__ float fast_tanh(float x){
  float e = __expf(2.f * x);
  return 1.f - __fdividef(2.f, e + 1.f);
}

// fp32 -> bf16 round-to-nearest-even (init kernel only)
__device__ __forceinline__ unsigned f2bf(float f){
  unsigned u = __float_as_uint(f);
  u = u + 0x7fffu + ((u >> 16) & 1u);
  return u >> 16;
}

// pack two fp32 -> one dword of 2 bf16 (RNE) via the HW packer
__device__ __forceinline__ unsigned cvt_pk_bf16(float lo, float hi){
  unsigned r;
  asm("v_cvt_pk_bf16_f32 %0, %1, %2" : "=v"(r) : "v"(lo), "v"(hi));
  return r;
}

// ---------------------------------------------------------------------------
// init: pre-pack at1w / rc1w into per-lane MFMA B-fragment layout (bf16).
// fragbuf[((path*2+nt)*2+kt)*64 + lane] = uint4 of 8 bf16: k=kt*32+qg*8+e,
// col nt*16+c16  (c16=lane&15, qg=lane>>4).
// ---------------------------------------------------------------------------
__global__ __launch_bounds__(512)
void pack_kernel(const float* __restrict__ at1w, const float* __restrict__ rc1w,
                 uint4* __restrict__ fragbuf)
{
  int t = threadIdx.x;             // 0..511
  int lane = t & 63, kt = (t>>6)&1, nt = (t>>7)&1, path = t>>8;
  const float* src = path ? rc1w : at1w;
  int c16 = lane & 15, qg = lane >> 4;
  unsigned r[4];
  #pragma unroll
  for (int e2 = 0; e2 < 4; e2++){
    int k0 = kt*32 + qg*8 + e2*2;
    unsigned lo = f2bf(src[k0*32     + nt*16 + c16]);
    unsigned hi = f2bf(src[(k0+1)*32 + nt*16 + c16]);
    r[e2] = lo | (hi << 16);
  }
  uint4 v; v.x=r[0]; v.y=r[1]; v.z=r[2]; v.w=r[3];
  fragbuf[((path*2+nt)*2+kt)*64 + lane] = v;
}

// ---------------------------------------------------------------------------
__global__ __launch_bounds__(128)
void encode_kernel(const float* __restrict__ x, const float* __restrict__ sew,
                   const float* __restrict__ seb, float* __restrict__ present,
                   float* __restrict__ S0)
{
  int bt = blockIdx.x;        // b*4 + t
  int o  = threadIdx.x;       // 0..127
  const float* xv = x + (size_t)(bt * NOBJ + o) * 4;
  float x0 = xv[0], x1 = xv[1], x2 = xv[2], x3 = xv[3];
  float* pr = present + (size_t)(bt * NOBJ + o) * 4;
  pr[0] = x0; pr[1] = x1; pr[2] = x2; pr[3] = x3;
  int t = bt & 3, b = bt >> 2;
  if (t == 3) {
    float* s = S0 + (size_t)(b * NOBJ + o) * 32;
    s[0] = x0; s[1] = x1; s[2] = x2; s[3] = x3;
    #pragma unroll
    for (int k = 4; k < 32; k++)
      s[k] = seb[k] + x0*sew[k] + x1*sew[32+k] + x2*sew[64+k] + x3*sew[96+k];
  }
}

// ---------------------------------------------------------------------------
// per-object projections: P1r/P1a (hoisted layer-1 i-halves), P2ar (j-halves,
// interleaved float2, transposed [b][k][j]), self_dyn, positions.
// ---------------------------------------------------------------------------
__device__ void project_body(int tid, int bo, const float* __restrict__ s_sh,
                             float* __restrict__ h_sh, const W& w,
                             float* __restrict__ SD,
                             float* __restrict__ P1R, float* __restrict__ P1A,
                             float* __restrict__ P2AR,
                             float* __restrict__ PX, float* __restrict__ PY)
{
  int b = bo >> 7, o = bo & 127;
  if (tid < 64) {
    float a1r = w.rc0b[tid], a2r = 0.f, a1a = w.at0b[tid], a2a = 0.f;
    #pragma unroll
    for (int c = 0; c < 32; c++) {
      float sv = s_sh[c];
      a1r += sv * w.rc0w[c*64 + tid];
      a2r += sv * w.rc0w[(32+c)*64 + tid];
      a1a += sv * w.at0w[c*64 + tid];
      a2a += sv * w.at0w[(32+c)*64 + tid];
    }
    P1R[(size_t)bo*64 + tid] = a1r;
    P1A[(size_t)bo*64 + tid] = a1a;
    float2 p; p.x = a2a; p.y = a2r;
    ((float2*)P2AR)[(size_t)(b*64 + tid)*NOBJ + o] = p;
  }
  if (tid < 32) {
    float acc = w.sc0b[tid];
    #pragma unroll
    for (int c = 0; c < 32; c++) acc += s_sh[c] * w.sc0w[c*32 + tid];
    h_sh[tid] = fmaxf(acc, 0.f);
  }
  __syncthreads();
  if (tid < 32) {
    float acc = w.sc1b[tid] + h_sh[tid];
    #pragma unroll
    for (int c = 0; c < 32; c++) acc += h_sh[c] * w.sc1w[c*32 + tid];
    SD[(size_t)bo*32 + tid] = acc;
  }
  if (tid == 0) { PX[bo] = s_sh[0]; PY[bo] = s_sh[1]; }
}

__global__ __launch_bounds__(64)
void project_kernel(const float* __restrict__ S, W w,
                    float* SD, float* P1R, float* P1A,
                    float* P2AR, float* PX, float* PY)
{
  __shared__ float s_sh[32], h_sh[32];
  int bo = blockIdx.x, tid = threadIdx.x;
  if (tid < 32) s_sh[tid] = S[(size_t)bo*32 + tid];
  __syncthreads();
  project_body(tid, bo, s_sh, h_sh, w, SD, P1R, P1A, P2AR, PX, PY);
}

// GEMM pass: [128x64] (LDS, bf16, swizzled) @ [64x32] (B-frags in regs).
// wave wv owns M-tiles wv*4..wv*4+3; A-frag: lane l = row (l&15), k-chunk l>>4.
#define GEMM_PASS(BF, COUT) do {                                              \
  _Pragma("unroll")                                                           \
  for (int mt = 0; mt < 4; mt++){                                             \
    int jr = (wv<<6) + (mt<<4) + c16;                                         \
    bfrag a0 = *((const bfrag*)((const char*)smem + (jr<<7) + (((qg  ) ^ (jr&7))<<4))); \
    bfrag a1 = *((const bfrag*)((const char*)smem + (jr<<7) + (((4+qg) ^ (jr&7))<<4))); \
    _Pragma("unroll")                                                         \
    for (int nt = 0; nt < 2; nt++){                                           \
      COUT[mt][nt] = __builtin_amdgcn_mfma_f32_16x16x32_bf16(a0, BF[nt][0], COUT[mt][nt], 0,0,0); \
      COUT[mt][nt] = __builtin_amdgcn_mfma_f32_16x16x32_bf16(a1, BF[nt][1], COUT[mt][nt], 0,0,0); \
    }                                                                         \
  }                                                                           \
} while(0)

// ---------------------------------------------------------------------------
// one rollout step.  block = (b,i), 128 threads (2 waves).
// Fused prep: one p2p pass computes both paths; att tile -> LDS, rel acts
// packed in 32 VGPRs, stored to the SAME tile after the att GEMM.
// ---------------------------------------------------------------------------
__global__ __launch_bounds__(128)
void step_kernel(const float* __restrict__ S_in,  const float* __restrict__ SD_in,
                 const float* __restrict__ P1R_in, const float* __restrict__ P1A_in,
                 const float* __restrict__ P2AR_in,
                 const float* __restrict__ PX_in,  const float* __restrict__ PY_in,
                 float* __restrict__ S_out, float* __restrict__ SD_out,
                 float* __restrict__ P1R_out, float* __restrict__ P1A_out,
                 float* __restrict__ P2AR_out,
                 float* __restrict__ PX_out, float* __restrict__ PY_out,
                 const uint4* __restrict__ fragbuf,
                 W w, float* __restrict__ out_roll, int tstep)
{
  __shared__ __align__(16) float smem[4352];   // [0,4096): 128x64 bf16 tile
  float* qbuf    = smem + 4096;  // 2 waves x (32 q + 1 A) = 66
  float* v0_sh   = smem + 4164;  // 32
  float* v1_sh   = smem + 4196;  // 32
  float* v2_sh   = smem + 4228;  // 32
  float* snew_sh = smem + 4260;  // 32
  float* h_sh    = smem + 4292;  // 32

  int bi = blockIdx.x;            // b*128 + i
  int b = bi >> 7, i = bi & 127;
  int tid = threadIdx.x;          // j
  int j = tid;
  int wv = tid >> 6, l = tid & 63;
  int c16 = l & 15, qg = l >> 4;  // MFMA lane coords

  // ---- geometry ----
  float px_i = S_in[(size_t)bi*32 + 0], py_i = S_in[(size_t)bi*32 + 1];
  float px_j = PX_in[b*NOBJ + j], py_j = PY_in[b*NOBJ + j];
  float dx = px_i - px_j, dy = py_i - py_j;
  float dist = sqrtf(dx*dx + dy*dy + 1e-10f);

  const float2* p2p = ((const float2*)P2AR_in) + (size_t)(b*64)*NOBJ + j;

  // ---- att B-fragments (pre-packed; 4 x 16B loads) ----
  bfrag bfA[2][2];
  #pragma unroll
  for (int nt = 0; nt < 2; nt++)
    #pragma unroll
    for (int kt = 0; kt < 2; kt++)
      bfA[nt][kt] = *((const bfrag*)&fragbuf[(nt*2+kt)*64 + l]);

  // ---- fused prep: one p2p pass -> att tile (LDS) + rel acts (regs) ----
  unsigned relpk[32];
  {
    const float* p1a_ = P1A_in + (size_t)bi*64;
    const float* p1r_ = P1R_in + (size_t)bi*64;
    const float* gA = w.at0w + 64*64;
    const float* gR = w.rc0w + 64*64;
    #pragma unroll
    for (int s = 0; s < 8; s++){
      unsigned aw[4];
      #pragma unroll
      for (int e2 = 0; e2 < 4; e2++){
        int k0 = s*8 + e2*2, k1 = k0 + 1;
        float2 pa0 = p2p[(size_t)k0*NOBJ];
        float2 pa1 = p2p[(size_t)k1*NOBJ];
        float preA0 = p1a_[k0] + pa0.x + dist*gA[k0] + dx*gA[64+k0] + dy*gA[128+k0];
        float preA1 = p1a_[k1] + pa1.x + dist*gA[k1] + dx*gA[64+k1] + dy*gA[128+k1];
        float preR0 = p1r_[k0] + pa0.y + dist*gR[k0] + dx*gR[64+k0] + dy*gR[128+k0];
        float preR1 = p1r_[k1] + pa1.y + dist*gR[k1] + dx*gR[64+k1] + dy*gR[128+k1];
        float aA0 = fast_tanh(preA0), aA1 = fast_tanh(preA1);
        float aR0 = fmaxf(preR0, 0.f), aR1 = fmaxf(preR1, 0.f);
        aw[e2] = cvt_pk_bf16(aA0, aA1);
        relpk[s*4 + e2] = cvt_pk_bf16(aR0, aR1);
      }
      uint4 pk; pk.x=aw[0]; pk.y=aw[1]; pk.z=aw[2]; pk.w=aw[3];
      *((uint4*)((char*)smem + (j<<7) + ((s ^ (j&7))<<4))) = pk;
    }
  }
  __syncthreads();

  // ================= attention GEMM =================
  f4t cA[4][2];
  #pragma unroll
  for (int mt = 0; mt < 4; mt++)
    #pragma unroll
    for (int nt = 0; nt < 2; nt++) cA[mt][nt] = (f4t){0.f,0.f,0.f,0.f};
  GEMM_PASS(bfA, cA);
  __syncthreads();   // all tile reads done

  // ---- store rel tile (overwrites att tile) + attv epilogue (reg-only) ----
  #pragma unroll
  for (int s = 0; s < 8; s++){
    uint4 pk; pk.x=relpk[s*4]; pk.y=relpk[s*4+1]; pk.z=relpk[s*4+2]; pk.w=relpk[s*4+3];
    *((uint4*)((char*)smem + (j<<7) + ((s ^ (j&7))<<4))) = pk;
  }

  float attv[16];
  {
    float bA0 = w.at1b[c16], bA1 = w.at1b[16 + c16];
    float w20 = w.at2w[c16], w21 = w.at2w[16 + c16];
    float a2b = w.at2b[0];
    #pragma unroll
    for (int mt = 0; mt < 4; mt++)
      #pragma unroll
      for (int reg = 0; reg < 4; reg++) {
        float s = fast_tanh(cA[mt][0][reg] + bA0) * w20
                + fast_tanh(cA[mt][1][reg] + bA1) * w21;
        s += __shfl_xor(s, 1); s += __shfl_xor(s, 2);
        s += __shfl_xor(s, 4); s += __shfl_xor(s, 8);
        int jj = wv*64 + mt*16 + qg*4 + reg;
        attv[mt*4 + reg] = (jj == i) ? 0.f : __expf(s + a2b);
      }
  }

  // ---- rel B-fragments (loaded late to cap register pressure) ----
  bfrag bfR[2][2];
  #pragma unroll
  for (int nt = 0; nt < 2; nt++)
    #pragma unroll
    for (int kt = 0; kt < 2; kt++)
      bfR[nt][kt] = *((const bfrag*)&fragbuf[(4 + nt*2+kt)*64 + l]);
  __syncthreads();

  // ================= relation GEMM =================
  f4t cR[4][2];
  #pragma unroll
  for (int mt = 0; mt < 4; mt++)
    #pragma unroll
    for (int nt = 0; nt < 2; nt++) cR[mt][nt] = (f4t){0.f,0.f,0.f,0.f};
  GEMM_PASS(bfR, cR);

  // epilogue: q = sum_j att_j * relu(r2pre_j), A = sum_j att_j
  {
    float bR0 = w.rc1b[c16], bR1 = w.rc1b[16 + c16];
    float q0 = 0.f, q1 = 0.f, Ap = 0.f;
    #pragma unroll
    for (int mt = 0; mt < 4; mt++)
      #pragma unroll
      for (int reg = 0; reg < 4; reg++) {
        float av = attv[mt*4 + reg]; Ap += av;
        q0 += av * fmaxf(cR[mt][0][reg] + bR0, 0.f);
        q1 += av * fmaxf(cR[mt][1][reg] + bR1, 0.f);
      }
    q0 += __shfl_xor(q0, 16); q0 += __shfl_xor(q0, 32);
    q1 += __shfl_xor(q1, 16); q1 += __shfl_xor(q1, 32);
    Ap += __shfl_xor(Ap, 16); Ap += __shfl_xor(Ap, 32);
    if (l < 16) { qbuf[wv*33 + l] = q0; qbuf[wv*33 + 16 + l] = q1; }
    if (l == 0) qbuf[wv*33 + 32] = Ap;
  }
  __syncthreads();

  // ---- per-object tail (32 threads) ----
  if (tid < 32) v2_sh[tid] = qbuf[tid] + qbuf[33 + tid];     // q combined
  __syncthreads();
  if (tid < 32) {                       // dyn = SD + q@rc2w + A*rc2b + q
    float A = qbuf[32] + qbuf[65];
    float acc = SD_in[(size_t)bi*32 + tid] + A * w.rc2b[tid] + v2_sh[tid];
    for (int k = 0; k < 32; k++) acc += v2_sh[k] * w.rc2w[k*32 + tid];
    v0_sh[tid] = acc;
  }
  __syncthreads();
  if (tid < 32) {                       // aff1
    float acc = w.af0b[tid];
    for (int k = 0; k < 32; k++) acc += v0_sh[k] * w.af0w[k*32 + tid];
    v1_sh[tid] = fast_tanh(acc);
  }
  __syncthreads();
  if (tid < 32) {                       // aff2
    float acc = w.af1b[tid];
    for (int k = 0; k < 32; k++) acc += v1_sh[k] * w.af1w[k*32 + tid];
    v2_sh[tid] = fast_tanh(acc) + v1_sh[tid];
  }
  __syncthreads();
  if (tid < 32) {                       // aff3
    float acc = w.af2b[tid];
    for (int k = 0; k < 32; k++) acc += v2_sh[k] * w.af2w[k*32 + tid];
    v0_sh[tid] = acc;
  }
  __syncthreads();
  if (tid < 32) {                       // out1 = tanh([aff3,s]@o0+b)
    float acc = w.o0b[tid];
    for (int k = 0; k < 32; k++) acc += v0_sh[k] * w.o0w[k*32 + tid];
    for (int k = 0; k < 32; k++) acc += S_in[(size_t)bi*32 + k] * w.o0w[(32+k)*32 + tid];
    v1_sh[tid] = fast_tanh(acc);
  }
  __syncthreads();
  if (tid < 32) {                       // res = out1@o1 + b + out1 (+s[:2])
    float acc = w.o1b[tid] + v1_sh[tid];
    for (int k = 0; k < 32; k++) acc += v1_sh[k] * w.o1w[k*32 + tid];
    if (tid < 2) acc += S_in[(size_t)bi*32 + tid];
    snew_sh[tid] = acc;
    S_out[(size_t)bi*32 + tid] = acc;
    if (tid < 4)
      out_roll[(size_t)((b*NROLL + tstep)*NOBJ + i)*4 + tid] = acc;
  }
  __syncthreads();

  // ---- fused projections of the NEW state for the next step ----
  project_body(tid, bi, snew_sh, h_sh, w,
               SD_out, P1R_out, P1A_out, P2AR_out, PX_out, PY_out);
}

// ---------------------------------------------------------------------------
extern "C" void kernel_launch(void* const* d_in, const int* in_sizes, int n_in,
                              void* d_out, int out_size, void* d_ws, size_t ws_size,
                              hipStream_t stream)
{
  const float* x    = (const float*)d_in[0];
  const float* sew  = (const float*)d_in[1];
  const float* seb  = (const float*)d_in[2];
  W w;
  w.sc0w=(const float*)d_in[3];  w.sc0b=(const float*)d_in[4];
  w.sc1w=(const float*)d_in[5];  w.sc1b=(const float*)d_in[6];
  w.rc0w=(const float*)d_in[7];  w.rc0b=(const float*)d_in[8];
  w.rc1w=(const float*)d_in[9];  w.rc1b=(const float*)d_in[10];
  w.rc2w=(const float*)d_in[11]; w.rc2b=(const float*)d_in[12];
  w.at0w=(const float*)d_in[13]; w.at0b=(const float*)d_in[14];
  w.at1w=(const float*)d_in[15]; w.at1b=(const float*)d_in[16];
  w.at2w=(const float*)d_in[17]; w.at2b=(const float*)d_in[18];
  w.af0w=(const float*)d_in[19]; w.af0b=(const float*)d_in[20];
  w.af1w=(const float*)d_in[21]; w.af1b=(const float*)d_in[22];
  w.af2w=(const float*)d_in[23]; w.af2b=(const float*)d_in[24];
  w.o0w =(const float*)d_in[25]; w.o0b =(const float*)d_in[26];
  w.o1w =(const float*)d_in[27]; w.o1b =(const float*)d_in[28];

  float* out = (float*)d_out;
  float* out_roll    = out;                              // (16,8,128,4)
  float* out_present = out + NB*NROLL*NOBJ*4;            // (16,4,128,4)

  float* ws = (float*)d_ws;
  size_t off = 0;
  auto alloc = [&](size_t n){ float* p = ws + off; off += n; return p; };
  float* S[2]    = { alloc(NB*NOBJ*32),   alloc(NB*NOBJ*32) };
  float* SD[2]   = { alloc(NB*NOBJ*32),   alloc(NB*NOBJ*32) };
  float* P1R[2]  = { alloc(NB*NOBJ*64),   alloc(NB*NOBJ*64) };
  float* P1A[2]  = { alloc(NB*NOBJ*64),   alloc(NB*NOBJ*64) };
  float* P2AR[2] = { alloc(NB*64*NOBJ*2), alloc(NB*64*NOBJ*2) };
  float* PX[2]   = { alloc(NB*NOBJ),      alloc(NB*NOBJ) };
  float* PY[2]   = { alloc(NB*NOBJ),      alloc(NB*NOBJ) };
  uint4* fragbuf = (uint4*)alloc(512 * 4);               // 8 KB packed B-frags
  (void)ws_size; (void)in_sizes; (void)n_in; (void)out_size;

  hipLaunchKernelGGL(pack_kernel, dim3(1), dim3(512), 0, stream,
                     w.at1w, w.rc1w, fragbuf);
  hipLaunchKernelGGL(encode_kernel, dim3(NB*4), dim3(NOBJ), 0, stream,
                     x, sew, seb, out_present, S[0]);
  hipLaunchKernelGGL(project_kernel, dim3(NB*NOBJ), dim3(64), 0, stream,
                     S[0], w, SD[0], P1R[0], P1A[0], P2AR[0], PX[0], PY[0]);

  for (int t = 0; t < NROLL; t++) {
    int a = t & 1, oo = 1 - a;
    hipLaunchKernelGGL(step_kernel, dim3(NB*NOBJ), dim3(128), 0, stream,
                       S[a], SD[a], P1R[a], P1A[a], P2AR[a], PX[a], PY[a],
                       S[oo], SD[oo], P1R[oo], P1A[oo], P2AR[oo], PX[oo], PY[oo],
                       fragbuf, w, out_roll, t);
  }
}

// Round 9
// 405.483 us; speedup vs baseline: 3.7046x; 1.0002x over previous
//
#include <hip/hip_runtime.h>
#include <math.h>

#define NB 16
#define NOBJ 128
#define NROLL 8

typedef short bfrag __attribute__((ext_vector_type(8)));   // 8 bf16 (4 VGPR)
typedef float f4t  __attribute__((ext_vector_type(4)));    // MFMA acc

struct W {
  const float *rc0w,*rc0b,*rc1w,*rc1b,*rc2w,*rc2b;
  const float *at0w,*at0b,*at1w,*at1b,*at2w,*at2b;
  const float *af0w,*af0b,*af1w,*af1b,*af2w,*af2b;
  const float *o0w,*o0b,*o1w,*o1b;
  const float *sc0w,*sc0b,*sc1w,*sc1b;
};

// tanh = 1 - 2/(e^{2x}+1), e^{2x} = 2^(x*2*log2 e): mul+exp+add+rcp+fma (5 inst)
__device__ __forceinline__ float fast_tanh(float x){
  float e = exp2f(x * 2.8853900817779268f);
  return fmaf(__builtin_amdgcn_rcpf(e + 1.f), -2.f, 1.f);
}

// fp32 -> bf16 round-to-nearest-even (init kernel only)
__device__ __forceinline__ unsigned f2bf(float f){
  unsigned u = __float_as_uint(f);
  u = u + 0x7fffu + ((u >> 16) & 1u);
  return u >> 16;
}

// pack two fp32 -> one dword of 2 bf16 (RNE) via the HW packer
__device__ __forceinline__ unsigned cvt_pk_bf16(float lo, float hi){
  unsigned r;
  asm("v_cvt_pk_bf16_f32 %0, %1, %2" : "=v"(r) : "v"(lo), "v"(hi));
  return r;
}

// ---------------------------------------------------------------------------
// init: pre-pack at1w / rc1w into per-lane MFMA B-fragment layout (bf16).
// ---------------------------------------------------------------------------
__global__ __launch_bounds__(512)
void pack_kernel(const float* __restrict__ at1w, const float* __restrict__ rc1w,
                 uint4* __restrict__ fragbuf)
{
  int t = threadIdx.x;             // 0..511
  int lane = t & 63, kt = (t>>6)&1, nt = (t>>7)&1, path = t>>8;
  const float* src = path ? rc1w : at1w;
  int c16 = lane & 15, qg = lane >> 4;
  unsigned r[4];
  #pragma unroll
  for (int e2 = 0; e2 < 4; e2++){
    int k0 = kt*32 + qg*8 + e2*2;
    unsigned lo = f2bf(src[k0*32     + nt*16 + c16]);
    unsigned hi = f2bf(src[(k0+1)*32 + nt*16 + c16]);
    r[e2] = lo | (hi << 16);
  }
  uint4 v; v.x=r[0]; v.y=r[1]; v.z=r[2]; v.w=r[3];
  fragbuf[((path*2+nt)*2+kt)*64 + lane] = v;
}

// ---------------------------------------------------------------------------
__global__ __launch_bounds__(128)
void encode_kernel(const float* __restrict__ x, const float* __restrict__ sew,
                   const float* __restrict__ seb, float* __restrict__ present,
                   float* __restrict__ S0)
{
  int bt = blockIdx.x;        // b*4 + t
  int o  = threadIdx.x;       // 0..127
  const float* xv = x + (size_t)(bt * NOBJ + o) * 4;
  float x0 = xv[0], x1 = xv[1], x2 = xv[2], x3 = xv[3];
  float* pr = present + (size_t)(bt * NOBJ + o) * 4;
  pr[0] = x0; pr[1] = x1; pr[2] = x2; pr[3] = x3;
  int t = bt & 3, b = bt >> 2;
  if (t == 3) {
    float* s = S0 + (size_t)(b * NOBJ + o) * 32;
    s[0] = x0; s[1] = x1; s[2] = x2; s[3] = x3;
    #pragma unroll
    for (int k = 4; k < 32; k++)
      s[k] = seb[k] + x0*sew[k] + x1*sew[32+k] + x2*sew[64+k] + x3*sew[96+k];
  }
}

// ---------------------------------------------------------------------------
// per-object projections.  Callable from >=128-thread blocks; local tid pt,
// per-object LDS buffers.  Internal barrier must be hit by ALL block threads.
// ---------------------------------------------------------------------------
__device__ void project_body(int pt, int bo, const float* __restrict__ s_sh,
                             float* __restrict__ h_sh, const W& w,
                             float* __restrict__ SD,
                             float* __restrict__ P1R, float* __restrict__ P1A,
                             float* __restrict__ P2AR,
                             float* __restrict__ PX, float* __restrict__ PY)
{
  int b = bo >> 7, o = bo & 127;
  if (pt < 64) {
    float a1r = w.rc0b[pt], a2r = 0.f, a1a = w.at0b[pt], a2a = 0.f;
    #pragma unroll
    for (int c = 0; c < 32; c++) {
      float sv = s_sh[c];
      a1r += sv * w.rc0w[c*64 + pt];
      a2r += sv * w.rc0w[(32+c)*64 + pt];
      a1a += sv * w.at0w[c*64 + pt];
      a2a += sv * w.at0w[(32+c)*64 + pt];
    }
    P1R[(size_t)bo*64 + pt] = a1r;
    P1A[(size_t)bo*64 + pt] = a1a;
    float2 pp; pp.x = a2a; pp.y = a2r;
    ((float2*)P2AR)[(size_t)(b*64 + pt)*NOBJ + o] = pp;
  }
  if (pt < 32) {
    float acc = w.sc0b[pt];
    #pragma unroll
    for (int c = 0; c < 32; c++) acc += s_sh[c] * w.sc0w[c*32 + pt];
    h_sh[pt] = fmaxf(acc, 0.f);
  }
  __syncthreads();
  if (pt < 32) {
    float acc = w.sc1b[pt] + h_sh[pt];
    #pragma unroll
    for (int c = 0; c < 32; c++) acc += h_sh[c] * w.sc1w[c*32 + pt];
    SD[(size_t)bo*32 + pt] = acc;
  }
  if (pt == 0) { PX[bo] = s_sh[0]; PY[bo] = s_sh[1]; }
}

__global__ __launch_bounds__(64)
void project_kernel(const float* __restrict__ S, W w,
                    float* SD, float* P1R, float* P1A,
                    float* P2AR, float* PX, float* PY)
{
  __shared__ float s_sh[32], h_sh[32];
  int bo = blockIdx.x, tid = threadIdx.x;
  if (tid < 32) s_sh[tid] = S[(size_t)bo*32 + tid];
  __syncthreads();
  project_body(tid, bo, s_sh, h_sh, w, SD, P1R, P1A, P2AR, PX, PY);
}

// GEMM pass over one object's 128x64 bf16 swizzled tile.
#define GEMM_PASS(TBASE, BF, COUT) do {                                       \
  _Pragma("unroll")                                                           \
  for (int mt = 0; mt < 4; mt++){                                             \
    int jr = (wv2<<6) + (mt<<4) + c16;                                        \
    const char* rb = (const char*)(TBASE) + (jr<<7);                          \
    bfrag a0 = *((const bfrag*)(rb + (((qg  ) ^ (jr&7))<<4)));                \
    bfrag a1 = *((const bfrag*)(rb + (((4+qg) ^ (jr&7))<<4)));                \
    _Pragma("unroll")                                                         \
    for (int nt = 0; nt < 2; nt++){                                           \
      COUT[mt][nt] = __builtin_amdgcn_mfma_f32_16x16x32_bf16(a0, BF[nt][0], COUT[mt][nt], 0,0,0); \
      COUT[mt][nt] = __builtin_amdgcn_mfma_f32_16x16x32_bf16(a1, BF[nt][1], COUT[mt][nt], 0,0,0); \
    }                                                                         \
  }                                                                           \
} while(0)

// ---------------------------------------------------------------------------
// one rollout step.  block = (b, object-pair), 256 threads (4 waves).
// Thread (g,lt): g = k-half, lt = j.  Each thread loads its 32 p2p float2
// ONCE and computes acts for BOTH objects (i0 = 2p, i1 = 2p+1).
// Waves 0,1 -> object 0 GEMMs; waves 2,3 -> object 1 (parallel).
// ---------------------------------------------------------------------------
__global__ __launch_bounds__(256)
void step_kernel(const float* __restrict__ S_in,  const float* __restrict__ SD_in,
                 const float* __restrict__ P1R_in, const float* __restrict__ P1A_in,
                 const float* __restrict__ P2AR_in,
                 const float* __restrict__ PX_in,  const float* __restrict__ PY_in,
                 float* __restrict__ S_out, float* __restrict__ SD_out,
                 float* __restrict__ P1R_out, float* __restrict__ P1A_out,
                 float* __restrict__ P2AR_out,
                 float* __restrict__ PX_out, float* __restrict__ PY_out,
                 const uint4* __restrict__ fragbuf,
                 W w, float* __restrict__ out_roll, int tstep)
{
  __shared__ __align__(16) float smem[8644];
  // [0,4096): obj0 tile (128x64 bf16, swizzled)   [4096,8192): obj1 tile
  float* qb_base = smem + 8192;   // 2 x 66
  float* vb_base = smem + 8324;   // 2 x 160 (v0,v1,v2,snew,h)

  int tid = threadIdx.x;
  int g   = tid >> 7;             // k-half for prep
  int lt  = tid & 127;            // j
  int w4  = tid >> 6;             // wave 0..3
  int obj = w4 >> 1;              // object for GEMM/attv/q phases
  int wv2 = w4 & 1;               // M-half within object
  int l = tid & 63, c16 = l & 15, qg = l >> 4;

  int p = blockIdx.x & 63, b = blockIdx.x >> 6;
  int i0 = 2*p;
  int bi0 = b*NOBJ + i0, bi1 = bi0 + 1;

  char* t0 = (char*)smem;
  char* t1 = (char*)smem + 16384;

  // ---- att B-fragments (pre-packed; 4 x 16B loads) ----
  bfrag bfA[2][2];
  #pragma unroll
  for (int nt = 0; nt < 2; nt++)
    #pragma unroll
    for (int kt = 0; kt < 2; kt++)
      bfA[nt][kt] = *((const bfrag*)&fragbuf[(nt*2+kt)*64 + l]);

  // ---- geometry for both objects ----
  float px0 = S_in[(size_t)bi0*32 + 0], py0 = S_in[(size_t)bi0*32 + 1];
  float px1 = S_in[(size_t)bi1*32 + 0], py1 = S_in[(size_t)bi1*32 + 1];
  float px_j = PX_in[b*NOBJ + lt], py_j = PY_in[b*NOBJ + lt];
  float dx0 = px0 - px_j, dy0 = py0 - py_j;
  float dx1 = px1 - px_j, dy1 = py1 - py_j;
  float dist0 = sqrtf(dx0*dx0 + dy0*dy0 + 1e-10f);
  float dist1 = sqrtf(dx1*dx1 + dy1*dy1 + 1e-10f);

  const float2* p2p = ((const float2*)P2AR_in) + (size_t)(b*64)*NOBJ + lt;
  const float* p1a0 = P1A_in + (size_t)bi0*64;
  const float* p1r0 = P1R_in + (size_t)bi0*64;
  const float* p1a1 = P1A_in + (size_t)bi1*64;
  const float* p1r1 = P1R_in + (size_t)bi1*64;
  const float* gA = w.at0w + 64*64;
  const float* gR = w.rc0w + 64*64;

  // ---- fused prep: 32 p2p loads -> acts for BOTH objects ----
  unsigned relpk[2][16];
  #pragma unroll
  for (int sl = 0; sl < 4; sl++){
    unsigned aw0[4], aw1[4];
    #pragma unroll
    for (int e2 = 0; e2 < 4; e2++){
      int k0 = g*32 + sl*8 + e2*2, k1 = k0 + 1;
      float2 pa0 = p2p[(size_t)k0*NOBJ];
      float2 pa1 = p2p[(size_t)k1*NOBJ];
      float gA0=gA[k0], gA1=gA[64+k0], gA2=gA[128+k0];
      float gB0=gA[k1], gB1=gA[64+k1], gB2=gA[128+k1];
      float hA0=gR[k0], hA1=gR[64+k0], hA2=gR[128+k0];
      float hB0=gR[k1], hB1=gR[64+k1], hB2=gR[128+k1];
      // object 0
      float a00 = fast_tanh(p1a0[k0] + pa0.x + dist0*gA0 + dx0*gA1 + dy0*gA2);
      float a01 = fast_tanh(p1a0[k1] + pa1.x + dist0*gB0 + dx0*gB1 + dy0*gB2);
      float r00 = fmaxf(p1r0[k0] + pa0.y + dist0*hA0 + dx0*hA1 + dy0*hA2, 0.f);
      float r01 = fmaxf(p1r0[k1] + pa1.y + dist0*hB0 + dx0*hB1 + dy0*hB2, 0.f);
      aw0[e2] = cvt_pk_bf16(a00, a01);
      relpk[0][sl*4 + e2] = cvt_pk_bf16(r00, r01);
      // object 1
      float a10 = fast_tanh(p1a1[k0] + pa0.x + dist1*gA0 + dx1*gA1 + dy1*gA2);
      float a11 = fast_tanh(p1a1[k1] + pa1.x + dist1*gB0 + dx1*gB1 + dy1*gB2);
      float r10 = fmaxf(p1r1[k0] + pa0.y + dist1*hA0 + dx1*hA1 + dy1*hA2, 0.f);
      float r11 = fmaxf(p1r1[k1] + pa1.y + dist1*hB0 + dx1*hB1 + dy1*hB2, 0.f);
      aw1[e2] = cvt_pk_bf16(a10, a11);
      relpk[1][sl*4 + e2] = cvt_pk_bf16(r10, r11);
    }
    int s = g*4 + sl;
    unsigned off = (lt<<7) + ((s ^ (lt&7))<<4);
    uint4 pk0; pk0.x=aw0[0]; pk0.y=aw0[1]; pk0.z=aw0[2]; pk0.w=aw0[3];
    uint4 pk1; pk1.x=aw1[0]; pk1.y=aw1[1]; pk1.z=aw1[2]; pk1.w=aw1[3];
    *((uint4*)(t0 + off)) = pk0;
    *((uint4*)(t1 + off)) = pk1;
  }
  __syncthreads();

  // ================= attention GEMMs (waves 0,1: obj0 | 2,3: obj1) ========
  const char* mytile = (const char*)smem + (obj<<14);
  f4t cA[4][2];
  #pragma unroll
  for (int mt = 0; mt < 4; mt++)
    #pragma unroll
    for (int nt = 0; nt < 2; nt++) cA[mt][nt] = (f4t){0.f,0.f,0.f,0.f};
  GEMM_PASS(mytile, bfA, cA);
  __syncthreads();   // tile reads done

  // ---- store rel tiles (overwrite) + attv epilogue (reg-only) ----
  #pragma unroll
  for (int sl = 0; sl < 4; sl++){
    int s = g*4 + sl;
    unsigned off = (lt<<7) + ((s ^ (lt&7))<<4);
    uint4 pk0; pk0.x=relpk[0][sl*4]; pk0.y=relpk[0][sl*4+1];
               pk0.z=relpk[0][sl*4+2]; pk0.w=relpk[0][sl*4+3];
    uint4 pk1; pk1.x=relpk[1][sl*4]; pk1.y=relpk[1][sl*4+1];
               pk1.z=relpk[1][sl*4+2]; pk1.w=relpk[1][sl*4+3];
    *((uint4*)(t0 + off)) = pk0;
    *((uint4*)(t1 + off)) = pk1;
  }

  int i_self = i0 + obj;
  float attv[16];
  {
    float bA0 = w.at1b[c16], bA1 = w.at1b[16 + c16];
    float w20 = w.at2w[c16], w21 = w.at2w[16 + c16];
    float a2b = w.at2b[0];
    #pragma unroll
    for (int mt = 0; mt < 4; mt++)
      #pragma unroll
      for (int reg = 0; reg < 4; reg++) {
        float s = fast_tanh(cA[mt][0][reg] + bA0) * w20
                + fast_tanh(cA[mt][1][reg] + bA1) * w21;
        s += __shfl_xor(s, 1); s += __shfl_xor(s, 2);
        s += __shfl_xor(s, 4); s += __shfl_xor(s, 8);
        int jj = wv2*64 + mt*16 + qg*4 + reg;
        attv[mt*4 + reg] = (jj == i_self) ? 0.f : __expf(s + a2b);
      }
  }

  // ---- rel B-fragments (loaded late) ----
  bfrag bfR[2][2];
  #pragma unroll
  for (int nt = 0; nt < 2; nt++)
    #pragma unroll
    for (int kt = 0; kt < 2; kt++)
      bfR[nt][kt] = *((const bfrag*)&fragbuf[(4 + nt*2+kt)*64 + l]);
  __syncthreads();   // rel tiles ready

  // ================= relation GEMMs =================
  f4t cR[4][2];
  #pragma unroll
  for (int mt = 0; mt < 4; mt++)
    #pragma unroll
    for (int nt = 0; nt < 2; nt++) cR[mt][nt] = (f4t){0.f,0.f,0.f,0.f};
  GEMM_PASS(mytile, bfR, cR);

  // epilogue: q = sum_j att_j * relu(r2pre_j), A = sum_j att_j
  {
    float bR0 = w.rc1b[c16], bR1 = w.rc1b[16 + c16];
    float q0 = 0.f, q1 = 0.f, Ap = 0.f;
    #pragma unroll
    for (int mt = 0; mt < 4; mt++)
      #pragma unroll
      for (int reg = 0; reg < 4; reg++) {
        float av = attv[mt*4 + reg]; Ap += av;
        q0 += av * fmaxf(cR[mt][0][reg] + bR0, 0.f);
        q1 += av * fmaxf(cR[mt][1][reg] + bR1, 0.f);
      }
    q0 += __shfl_xor(q0, 16); q0 += __shfl_xor(q0, 32);
    q1 += __shfl_xor(q1, 16); q1 += __shfl_xor(q1, 32);
    Ap += __shfl_xor(Ap, 16); Ap += __shfl_xor(Ap, 32);
    float* qb = qb_base + obj*66;
    if (l < 16) { qb[wv2*33 + l] = q0; qb[wv2*33 + 16 + l] = q1; }
    if (l == 0) qb[wv2*33 + 32] = Ap;
  }
  __syncthreads();

  // ---- per-object tails: og=0 on wave0 lanes, og=1 on wave2 lanes ----
  int og = tid >> 7, pt = tid & 127;
  int bio = bi0 + og;
  float* qbo  = qb_base + og*66;
  float* v0_sh = vb_base + og*160;
  float* v1_sh = v0_sh + 32;
  float* v2_sh = v0_sh + 64;
  float* snew_sh = v0_sh + 96;
  float* h_sh = v0_sh + 128;

  if (pt < 32) v2_sh[pt] = qbo[pt] + qbo[33 + pt];     // q combined
  __syncthreads();
  if (pt < 32) {                       // dyn = SD + q@rc2w + A*rc2b + q
    float A = qbo[32] + qbo[65];
    float acc = SD_in[(size_t)bio*32 + pt] + A * w.rc2b[pt] + v2_sh[pt];
    for (int k = 0; k < 32; k++) acc += v2_sh[k] * w.rc2w[k*32 + pt];
    v0_sh[pt] = acc;
  }
  __syncthreads();
  if (pt < 32) {                       // aff1
    float acc = w.af0b[pt];
    for (int k = 0; k < 32; k++) acc += v0_sh[k] * w.af0w[k*32 + pt];
    v1_sh[pt] = fast_tanh(acc);
  }
  __syncthreads();
  if (pt < 32) {                       // aff2
    float acc = w.af1b[pt];
    for (int k = 0; k < 32; k++) acc += v1_sh[k] * w.af1w[k*32 + pt];
    v2_sh[pt] = fast_tanh(acc) + v1_sh[pt];
  }
  __syncthreads();
  if (pt < 32) {                       // aff3
    float acc = w.af2b[pt];
    for (int k = 0; k < 32; k++) acc += v2_sh[k] * w.af2w[k*32 + pt];
    v0_sh[pt] = acc;
  }
  __syncthreads();
  if (pt < 32) {                       // out1 = tanh([aff3,s]@o0+b)
    float acc = w.o0b[pt];
    for (int k = 0; k < 32; k++) acc += v0_sh[k] * w.o0w[k*32 + pt];
    for (int k = 0; k < 32; k++) acc += S_in[(size_t)bio*32 + k] * w.o0w[(32+k)*32 + pt];
    v1_sh[pt] = fast_tanh(acc);
  }
  __syncthreads();
  if (pt < 32) {                       // res = out1@o1 + b + out1 (+s[:2])
    float acc = w.o1b[pt] + v1_sh[pt];
    for (int k = 0; k < 32; k++) acc += v1_sh[k] * w.o1w[k*32 + pt];
    if (pt < 2) acc += S_in[(size_t)bio*32 + pt];
    snew_sh[pt] = acc;
    S_out[(size_t)bio*32 + pt] = acc;
    if (pt < 4)
      out_roll[(size_t)((b*NROLL + tstep)*NOBJ + (i_self - obj + og))*4 + pt] = acc;
  }
  __syncthreads();

  // ---- fused projections of the NEW states (both objects in parallel) ----
  project_body(pt, bio, snew_sh, h_sh, w,
               SD_out, P1R_out, P1A_out, P2AR_out, PX_out, PY_out);
}

// ---------------------------------------------------------------------------
extern "C" void kernel_launch(void* const* d_in, const int* in_sizes, int n_in,
                              void* d_out, int out_size, void* d_ws, size_t ws_size,
                              hipStream_t stream)
{
  const float* x    = (const float*)d_in[0];
  const float* sew  = (const float*)d_in[1];
  const float* seb  = (const float*)d_in[2];
  W w;
  w.sc0w=(const float*)d_in[3];  w.sc0b=(const float*)d_in[4];
  w.sc1w=(const float*)d_in[5];  w.sc1b=(const float*)d_in[6];
  w.rc0w=(const float*)d_in[7];  w.rc0b=(const float*)d_in[8];
  w.rc1w=(const float*)d_in[9];  w.rc1b=(const float*)d_in[10];
  w.rc2w=(const float*)d_in[11]; w.rc2b=(const float*)d_in[12];
  w.at0w=(const float*)d_in[13]; w.at0b=(const float*)d_in[14];
  w.at1w=(const float*)d_in[15]; w.at1b=(const float*)d_in[16];
  w.at2w=(const float*)d_in[17]; w.at2b=(const float*)d_in[18];
  w.af0w=(const float*)d_in[19]; w.af0b=(const float*)d_in[20];
  w.af1w=(const float*)d_in[21]; w.af1b=(const float*)d_in[22];
  w.af2w=(const float*)d_in[23]; w.af2b=(const float*)d_in[24];
  w.o0w =(const float*)d_in[25]; w.o0b =(const float*)d_in[26];
  w.o1w =(const float*)d_in[27]; w.o1b =(const float*)d_in[28];

  float* out = (float*)d_out;
  float* out_roll    = out;                              // (16,8,128,4)
  float* out_present = out + NB*NROLL*NOBJ*4;            // (16,4,128,4)

  float* ws = (float*)d_ws;
  size_t off = 0;
  auto alloc = [&](size_t n){ float* p = ws + off; off += n; return p; };
  float* S[2]    = { alloc(NB*NOBJ*32),   alloc(NB*NOBJ*32) };
  float* SD[2]   = { alloc(NB*NOBJ*32),   alloc(NB*NOBJ*32) };
  float* P1R[2]  = { alloc(NB*NOBJ*64),   alloc(NB*NOBJ*64) };
  float* P1A[2]  = { alloc(NB*NOBJ*64),   alloc(NB*NOBJ*64) };
  float* P2AR[2] = { alloc(NB*64*NOBJ*2), alloc(NB*64*NOBJ*2) };
  float* PX[2]   = { alloc(NB*NOBJ),      alloc(NB*NOBJ) };
  float* PY[2]   = { alloc(NB*NOBJ),      alloc(NB*NOBJ) };
  uint4* fragbuf = (uint4*)alloc(512 * 4);               // 8 KB packed B-frags
  (void)ws_size; (void)in_sizes; (void)n_in; (void)out_size;

  hipLaunchKernelGGL(pack_kernel, dim3(1), dim3(512), 0, stream,
                     w.at1w, w.rc1w, fragbuf);
  hipLaunchKernelGGL(encode_kernel, dim3(NB*4), dim3(NOBJ), 0, stream,
                     x, sew, seb, out_present, S[0]);
  hipLaunchKernelGGL(project_kernel, dim3(NB*NOBJ), dim3(64), 0, stream,
                     S[0], w, SD[0], P1R[0], P1A[0], P2AR[0], PX[0], PY[0]);

  for (int t = 0; t < NROLL; t++) {
    int a = t & 1, oo = 1 - a;
    hipLaunchKernelGGL(step_kernel, dim3(NB*NOBJ/2), dim3(256), 0, stream,
                       S[a], SD[a], P1R[a], P1A[a], P2AR[a], PX[a], PY[a],
                       S[oo], SD[oo], P1R[oo], P1A[oo], P2AR[oo], PX[oo], PY[oo],
                       fragbuf, w, out_roll, t);
  }
}

// Round 10
// 404.063 us; speedup vs baseline: 3.7176x; 1.0035x over previous
//
#include <hip/hip_runtime.h>
#include <math.h>

#define NB 16
#define NOBJ 128
#define NROLL 8

typedef short bfrag __attribute__((ext_vector_type(8)));   // 8 bf16 (4 VGPR)
typedef float f4t  __attribute__((ext_vector_type(4)));    // MFMA acc

struct W {
  const float *rc0w,*rc0b,*rc1w,*rc1b,*rc2w,*rc2b;
  const float *at0w,*at0b,*at1w,*at1b,*at2w,*at2b;
  const float *af0w,*af0b,*af1w,*af1b,*af2w,*af2b;
  const float *o0w,*o0b,*o1w,*o1b;
  const float *sc0w,*sc0b,*sc1w,*sc1b;
};

// tanh = 1 - 2/(e^{2x}+1), e^{2x} = 2^(x*2*log2 e)
__device__ __forceinline__ float fast_tanh(float x){
  float e = exp2f(x * 2.8853900817779268f);
  return fmaf(__builtin_amdgcn_rcpf(e + 1.f), -2.f, 1.f);
}

// fp32 -> bf16 round-to-nearest-even (init kernel only)
__device__ __forceinline__ unsigned f2bf(float f){
  unsigned u = __float_as_uint(f);
  u = u + 0x7fffu + ((u >> 16) & 1u);
  return u >> 16;
}

// pack two fp32 -> one dword of 2 bf16 (RNE) via the HW packer
__device__ __forceinline__ unsigned cvt_pk_bf16(float lo, float hi){
  unsigned r;
  asm("v_cvt_pk_bf16_f32 %0, %1, %2" : "=v"(r) : "v"(lo), "v"(hi));
  return r;
}

// ---------------------------------------------------------------------------
// init: pre-pack at1w / rc1w into per-lane MFMA B-fragment layout (bf16).
// ---------------------------------------------------------------------------
__global__ __launch_bounds__(512)
void pack_kernel(const float* __restrict__ at1w, const float* __restrict__ rc1w,
                 uint4* __restrict__ fragbuf)
{
  int t = threadIdx.x;             // 0..511
  int lane = t & 63, kt = (t>>6)&1, nt = (t>>7)&1, path = t>>8;
  const float* src = path ? rc1w : at1w;
  int c16 = lane & 15, qg = lane >> 4;
  unsigned r[4];
  #pragma unroll
  for (int e2 = 0; e2 < 4; e2++){
    int k0 = kt*32 + qg*8 + e2*2;
    unsigned lo = f2bf(src[k0*32     + nt*16 + c16]);
    unsigned hi = f2bf(src[(k0+1)*32 + nt*16 + c16]);
    r[e2] = lo | (hi << 16);
  }
  uint4 v; v.x=r[0]; v.y=r[1]; v.z=r[2]; v.w=r[3];
  fragbuf[((path*2+nt)*2+kt)*64 + lane] = v;
}

// ---------------------------------------------------------------------------
__global__ __launch_bounds__(128)
void encode_kernel(const float* __restrict__ x, const float* __restrict__ sew,
                   const float* __restrict__ seb, float* __restrict__ present,
                   float* __restrict__ S0)
{
  int bt = blockIdx.x;        // b*4 + t
  int o  = threadIdx.x;       // 0..127
  const float* xv = x + (size_t)(bt * NOBJ + o) * 4;
  float x0 = xv[0], x1 = xv[1], x2 = xv[2], x3 = xv[3];
  float* pr = present + (size_t)(bt * NOBJ + o) * 4;
  pr[0] = x0; pr[1] = x1; pr[2] = x2; pr[3] = x3;
  int t = bt & 3, b = bt >> 2;
  if (t == 3) {
    float* s = S0 + (size_t)(b * NOBJ + o) * 32;
    s[0] = x0; s[1] = x1; s[2] = x2; s[3] = x3;
    #pragma unroll
    for (int k = 4; k < 32; k++)
      s[k] = seb[k] + x0*sew[k] + x1*sew[32+k] + x2*sew[64+k] + x3*sew[96+k];
  }
}

// ---------------------------------------------------------------------------
// per-object projections (unchanged).
// ---------------------------------------------------------------------------
__device__ void project_body(int pt, int bo, const float* __restrict__ s_sh,
                             float* __restrict__ h_sh, const W& w,
                             float* __restrict__ SD,
                             float* __restrict__ P1R, float* __restrict__ P1A,
                             float* __restrict__ P2AR,
                             float* __restrict__ PX, float* __restrict__ PY)
{
  int b = bo >> 7, o = bo & 127;
  if (pt < 64) {
    float a1r = w.rc0b[pt], a2r = 0.f, a1a = w.at0b[pt], a2a = 0.f;
    #pragma unroll
    for (int c = 0; c < 32; c++) {
      float sv = s_sh[c];
      a1r += sv * w.rc0w[c*64 + pt];
      a2r += sv * w.rc0w[(32+c)*64 + pt];
      a1a += sv * w.at0w[c*64 + pt];
      a2a += sv * w.at0w[(32+c)*64 + pt];
    }
    P1R[(size_t)bo*64 + pt] = a1r;
    P1A[(size_t)bo*64 + pt] = a1a;
    float2 pp; pp.x = a2a; pp.y = a2r;
    ((float2*)P2AR)[(size_t)(b*64 + pt)*NOBJ + o] = pp;
  }
  if (pt < 32) {
    float acc = w.sc0b[pt];
    #pragma unroll
    for (int c = 0; c < 32; c++) acc += s_sh[c] * w.sc0w[c*32 + pt];
    h_sh[pt] = fmaxf(acc, 0.f);
  }
  __syncthreads();
  if (pt < 32) {
    float acc = w.sc1b[pt] + h_sh[pt];
    #pragma unroll
    for (int c = 0; c < 32; c++) acc += h_sh[c] * w.sc1w[c*32 + pt];
    SD[(size_t)bo*32 + pt] = acc;
  }
  if (pt == 0) { PX[bo] = s_sh[0]; PY[bo] = s_sh[1]; }
}

__global__ __launch_bounds__(64)
void project_kernel(const float* __restrict__ S, W w,
                    float* SD, float* P1R, float* P1A,
                    float* P2AR, float* PX, float* PY)
{
  __shared__ float s_sh[32], h_sh[32];
  int bo = blockIdx.x, tid = threadIdx.x;
  if (tid < 32) s_sh[tid] = S[(size_t)bo*32 + tid];
  __syncthreads();
  project_body(tid, bo, s_sh, h_sh, w, SD, P1R, P1A, P2AR, PX, PY);
}

// GEMM pass over one object's 128x64 bf16 swizzled tile.
#define GEMM_PASS(TBASE, BF, COUT) do {                                       \
  _Pragma("unroll")                                                           \
  for (int mt = 0; mt < 4; mt++){                                             \
    int jr = (wv2<<6) + (mt<<4) + c16;                                        \
    const char* rb = (const char*)(TBASE) + (jr<<7);                          \
    bfrag a0 = *((const bfrag*)(rb + (((qg  ) ^ (jr&7))<<4)));                \
    bfrag a1 = *((const bfrag*)(rb + (((4+qg) ^ (jr&7))<<4)));                \
    _Pragma("unroll")                                                         \
    for (int nt = 0; nt < 2; nt++){                                           \
      COUT[mt][nt] = __builtin_amdgcn_mfma_f32_16x16x32_bf16(a0, BF[nt][0], COUT[mt][nt], 0,0,0); \
      COUT[mt][nt] = __builtin_amdgcn_mfma_f32_16x16x32_bf16(a1, BF[nt][1], COUT[mt][nt], 0,0,0); \
    }                                                                         \
  }                                                                           \
} while(0)

// ---------------------------------------------------------------------------
// one rollout step.  block = (b, object-pair), 256 threads (4 waves).
// LDS = exactly 32 KB (two 16 KB tiles); tail scratch ALIASED into tile0
// after GEMM2 (extra barrier guards the overwrite) -> 5 blocks/CU.
// ---------------------------------------------------------------------------
__global__ __launch_bounds__(256, 5)
void step_kernel(const float* __restrict__ S_in,  const float* __restrict__ SD_in,
                 const float* __restrict__ P1R_in, const float* __restrict__ P1A_in,
                 const float* __restrict__ P2AR_in,
                 const float* __restrict__ PX_in,  const float* __restrict__ PY_in,
                 float* __restrict__ S_out, float* __restrict__ SD_out,
                 float* __restrict__ P1R_out, float* __restrict__ P1A_out,
                 float* __restrict__ P2AR_out,
                 float* __restrict__ PX_out, float* __restrict__ PY_out,
                 const uint4* __restrict__ fragbuf,
                 W w, float* __restrict__ out_roll, int tstep)
{
  __shared__ __align__(16) float smem[8192];   // EXACTLY 32 KB
  // [0,4096): obj0 tile   [4096,8192): obj1 tile
  // after GEMM2, tile0 is reused: qb at [0,132), vb at [512, 512+320)
  float* qb_base = smem;
  float* vb_base = smem + 512;

  int tid = threadIdx.x;
  int g   = tid >> 7;             // k-half for prep
  int lt  = tid & 127;            // j
  int w4  = tid >> 6;             // wave 0..3
  int obj = w4 >> 1;              // object for GEMM/attv/q phases
  int wv2 = w4 & 1;               // M-half within object
  int l = tid & 63, c16 = l & 15, qg = l >> 4;

  int p = blockIdx.x & 63, b = blockIdx.x >> 6;
  int i0 = 2*p;
  int bi0 = b*NOBJ + i0, bi1 = bi0 + 1;

  char* t0 = (char*)smem;
  char* t1 = (char*)smem + 16384;

  // ---- att B-fragments (pre-packed; 4 x 16B loads) ----
  bfrag bfA[2][2];
  #pragma unroll
  for (int nt = 0; nt < 2; nt++)
    #pragma unroll
    for (int kt = 0; kt < 2; kt++)
      bfA[nt][kt] = *((const bfrag*)&fragbuf[(nt*2+kt)*64 + l]);

  // ---- geometry for both objects ----
  float px0 = S_in[(size_t)bi0*32 + 0], py0 = S_in[(size_t)bi0*32 + 1];
  float px1 = S_in[(size_t)bi1*32 + 0], py1 = S_in[(size_t)bi1*32 + 1];
  float px_j = PX_in[b*NOBJ + lt], py_j = PY_in[b*NOBJ + lt];
  float dx0 = px0 - px_j, dy0 = py0 - py_j;
  float dx1 = px1 - px_j, dy1 = py1 - py_j;
  float dist0 = sqrtf(dx0*dx0 + dy0*dy0 + 1e-10f);
  float dist1 = sqrtf(dx1*dx1 + dy1*dy1 + 1e-10f);

  const float2* p2p = ((const float2*)P2AR_in) + (size_t)(b*64)*NOBJ + lt;
  const float* p1a0 = P1A_in + (size_t)bi0*64;
  const float* p1r0 = P1R_in + (size_t)bi0*64;
  const float* p1a1 = P1A_in + (size_t)bi1*64;
  const float* p1r1 = P1R_in + (size_t)bi1*64;
  const float* gA = w.at0w + 64*64;
  const float* gR = w.rc0w + 64*64;

  // ---- fused prep: 32 p2p loads -> acts for BOTH objects ----
  unsigned relpk[2][16];
  #pragma unroll
  for (int sl = 0; sl < 4; sl++){
    unsigned aw0[4], aw1[4];
    #pragma unroll
    for (int e2 = 0; e2 < 4; e2++){
      int k0 = g*32 + sl*8 + e2*2, k1 = k0 + 1;
      float2 pa0 = p2p[(size_t)k0*NOBJ];
      float2 pa1 = p2p[(size_t)k1*NOBJ];
      float gA0=gA[k0], gA1=gA[64+k0], gA2=gA[128+k0];
      float gB0=gA[k1], gB1=gA[64+k1], gB2=gA[128+k1];
      float hA0=gR[k0], hA1=gR[64+k0], hA2=gR[128+k0];
      float hB0=gR[k1], hB1=gR[64+k1], hB2=gR[128+k1];
      // object 0
      float a00 = fast_tanh(p1a0[k0] + pa0.x + dist0*gA0 + dx0*gA1 + dy0*gA2);
      float a01 = fast_tanh(p1a0[k1] + pa1.x + dist0*gB0 + dx0*gB1 + dy0*gB2);
      float r00 = fmaxf(p1r0[k0] + pa0.y + dist0*hA0 + dx0*hA1 + dy0*hA2, 0.f);
      float r01 = fmaxf(p1r0[k1] + pa1.y + dist0*hB0 + dx0*hB1 + dy0*hB2, 0.f);
      aw0[e2] = cvt_pk_bf16(a00, a01);
      relpk[0][sl*4 + e2] = cvt_pk_bf16(r00, r01);
      // object 1
      float a10 = fast_tanh(p1a1[k0] + pa0.x + dist1*gA0 + dx1*gA1 + dy1*gA2);
      float a11 = fast_tanh(p1a1[k1] + pa1.x + dist1*gB0 + dx1*gB1 + dy1*gB2);
      float r10 = fmaxf(p1r1[k0] + pa0.y + dist1*hA0 + dx1*hA1 + dy1*hA2, 0.f);
      float r11 = fmaxf(p1r1[k1] + pa1.y + dist1*hB0 + dx1*hB1 + dy1*hB2, 0.f);
      aw1[e2] = cvt_pk_bf16(a10, a11);
      relpk[1][sl*4 + e2] = cvt_pk_bf16(r10, r11);
    }
    int s = g*4 + sl;
    unsigned off = (lt<<7) + ((s ^ (lt&7))<<4);
    uint4 pk0; pk0.x=aw0[0]; pk0.y=aw0[1]; pk0.z=aw0[2]; pk0.w=aw0[3];
    uint4 pk1; pk1.x=aw1[0]; pk1.y=aw1[1]; pk1.z=aw1[2]; pk1.w=aw1[3];
    *((uint4*)(t0 + off)) = pk0;
    *((uint4*)(t1 + off)) = pk1;
  }
  __syncthreads();

  // ================= attention GEMMs (waves 0,1: obj0 | 2,3: obj1) ========
  const char* mytile = (const char*)smem + (obj<<14);
  f4t cA[4][2];
  #pragma unroll
  for (int mt = 0; mt < 4; mt++)
    #pragma unroll
    for (int nt = 0; nt < 2; nt++) cA[mt][nt] = (f4t){0.f,0.f,0.f,0.f};
  GEMM_PASS(mytile, bfA, cA);
  __syncthreads();   // tile reads done

  // ---- store rel tiles (overwrite) + attv epilogue (reg-only) ----
  #pragma unroll
  for (int sl = 0; sl < 4; sl++){
    int s = g*4 + sl;
    unsigned off = (lt<<7) + ((s ^ (lt&7))<<4);
    uint4 pk0; pk0.x=relpk[0][sl*4]; pk0.y=relpk[0][sl*4+1];
               pk0.z=relpk[0][sl*4+2]; pk0.w=relpk[0][sl*4+3];
    uint4 pk1; pk1.x=relpk[1][sl*4]; pk1.y=relpk[1][sl*4+1];
               pk1.z=relpk[1][sl*4+2]; pk1.w=relpk[1][sl*4+3];
    *((uint4*)(t0 + off)) = pk0;
    *((uint4*)(t1 + off)) = pk1;
  }

  int i_self = i0 + obj;
  float attv[16];
  {
    float bA0 = w.at1b[c16], bA1 = w.at1b[16 + c16];
    float w20 = w.at2w[c16], w21 = w.at2w[16 + c16];
    float a2b = w.at2b[0];
    #pragma unroll
    for (int mt = 0; mt < 4; mt++)
      #pragma unroll
      for (int reg = 0; reg < 4; reg++) {
        float s = fast_tanh(cA[mt][0][reg] + bA0) * w20
                + fast_tanh(cA[mt][1][reg] + bA1) * w21;
        s += __shfl_xor(s, 1); s += __shfl_xor(s, 2);
        s += __shfl_xor(s, 4); s += __shfl_xor(s, 8);
        int jj = wv2*64 + mt*16 + qg*4 + reg;
        attv[mt*4 + reg] = (jj == i_self) ? 0.f : __expf(s + a2b);
      }
  }

  // ---- rel B-fragments (loaded late) ----
  bfrag bfR[2][2];
  #pragma unroll
  for (int nt = 0; nt < 2; nt++)
    #pragma unroll
    for (int kt = 0; kt < 2; kt++)
      bfR[nt][kt] = *((const bfrag*)&fragbuf[(4 + nt*2+kt)*64 + l]);
  __syncthreads();   // rel tiles ready

  // ================= relation GEMMs =================
  f4t cR[4][2];
  #pragma unroll
  for (int mt = 0; mt < 4; mt++)
    #pragma unroll
    for (int nt = 0; nt < 2; nt++) cR[mt][nt] = (f4t){0.f,0.f,0.f,0.f};
  GEMM_PASS(mytile, bfR, cR);

  // epilogue: q = sum_j att_j * relu(r2pre_j), A = sum_j att_j  (regs only)
  float q0 = 0.f, q1 = 0.f, Ap = 0.f;
  {
    float bR0 = w.rc1b[c16], bR1 = w.rc1b[16 + c16];
    #pragma unroll
    for (int mt = 0; mt < 4; mt++)
      #pragma unroll
      for (int reg = 0; reg < 4; reg++) {
        float av = attv[mt*4 + reg]; Ap += av;
        q0 += av * fmaxf(cR[mt][0][reg] + bR0, 0.f);
        q1 += av * fmaxf(cR[mt][1][reg] + bR1, 0.f);
      }
    q0 += __shfl_xor(q0, 16); q0 += __shfl_xor(q0, 32);
    q1 += __shfl_xor(q1, 16); q1 += __shfl_xor(q1, 32);
    Ap += __shfl_xor(Ap, 16); Ap += __shfl_xor(Ap, 32);
  }
  __syncthreads();   // ALL GEMM2 tile reads done -> safe to overwrite tile0
  {
    float* qb = qb_base + obj*66;
    if (l < 16) { qb[wv2*33 + l] = q0; qb[wv2*33 + 16 + l] = q1; }
    if (l == 0) qb[wv2*33 + 32] = Ap;
  }
  __syncthreads();

  // ---- per-object tails: og=0 on wave0, og=1 on wave2; 2-way k-split ----
  int og = tid >> 7, tl = tid & 127;
  int bio = bi0 + og;
  float* qbo  = qb_base + og*66;
  float* v0_sh = vb_base + og*160;
  float* v1_sh = v0_sh + 32;
  float* v2_sh = v0_sh + 64;
  float* snew_sh = v0_sh + 96;
  float* h_sh = v0_sh + 128;
  int outc = tl & 31, half = (tl >> 5) & 1;

  if (tl < 32) v2_sh[tl] = qbo[tl] + qbo[33 + tl];     // q combined
  __syncthreads();
  if (tl < 64) {                        // dyn = SD + q@rc2w + A*rc2b + q
    float acc = 0.f;
    #pragma unroll
    for (int k = 0; k < 16; k++) acc += v2_sh[half*16+k] * w.rc2w[(half*16+k)*32 + outc];
    acc += __shfl_xor(acc, 32);
    if (!half) {
      float A = qbo[32] + qbo[65];
      v0_sh[outc] = SD_in[(size_t)bio*32 + outc] + A * w.rc2b[outc] + v2_sh[outc] + acc;
    }
  }
  __syncthreads();
  if (tl < 64) {                        // aff1
    float acc = 0.f;
    #pragma unroll
    for (int k = 0; k < 16; k++) acc += v0_sh[half*16+k] * w.af0w[(half*16+k)*32 + outc];
    acc += __shfl_xor(acc, 32);
    if (!half) v1_sh[outc] = fast_tanh(acc + w.af0b[outc]);
  }
  __syncthreads();
  if (tl < 64) {                        // aff2
    float acc = 0.f;
    #pragma unroll
    for (int k = 0; k < 16; k++) acc += v1_sh[half*16+k] * w.af1w[(half*16+k)*32 + outc];
    acc += __shfl_xor(acc, 32);
    if (!half) v2_sh[outc] = fast_tanh(acc + w.af1b[outc]) + v1_sh[outc];
  }
  __syncthreads();
  if (tl < 64) {                        // aff3
    float acc = 0.f;
    #pragma unroll
    for (int k = 0; k < 16; k++) acc += v2_sh[half*16+k] * w.af2w[(half*16+k)*32 + outc];
    acc += __shfl_xor(acc, 32);
    if (!half) v0_sh[outc] = acc + w.af2b[outc];
  }
  __syncthreads();
  if (tl < 64) {                        // out1 = tanh([aff3,s]@o0+b), K=64
    float acc = 0.f;
    #pragma unroll
    for (int k = 0; k < 32; k++) {
      float src = half ? S_in[(size_t)bio*32 + k] : v0_sh[k];
      acc += src * w.o0w[(half*32+k)*32 + outc];
    }
    acc += __shfl_xor(acc, 32);
    if (!half) v1_sh[outc] = fast_tanh(acc + w.o0b[outc]);
  }
  __syncthreads();
  if (tl < 64) {                        // res = out1@o1 + b + out1 (+s[:2])
    float acc = 0.f;
    #pragma unroll
    for (int k = 0; k < 16; k++) acc += v1_sh[half*16+k] * w.o1w[(half*16+k)*32 + outc];
    acc += __shfl_xor(acc, 32);
    if (!half) {
      acc += w.o1b[outc] + v1_sh[outc];
      if (outc < 2) acc += S_in[(size_t)bio*32 + outc];
      snew_sh[outc] = acc;
      S_out[(size_t)bio*32 + outc] = acc;
      if (outc < 4)
        out_roll[(size_t)((b*NROLL + tstep)*NOBJ + (i0 + og))*4 + outc] = acc;
    }
  }
  __syncthreads();

  // ---- fused projections of the NEW states (both objects in parallel) ----
  project_body(tl, bio, snew_sh, h_sh, w,
               SD_out, P1R_out, P1A_out, P2AR_out, PX_out, PY_out);
}

// ---------------------------------------------------------------------------
extern "C" void kernel_launch(void* const* d_in, const int* in_sizes, int n_in,
                              void* d_out, int out_size, void* d_ws, size_t ws_size,
                              hipStream_t stream)
{
  const float* x    = (const float*)d_in[0];
  const float* sew  = (const float*)d_in[1];
  const float* seb  = (const float*)d_in[2];
  W w;
  w.sc0w=(const float*)d_in[3];  w.sc0b=(const float*)d_in[4];
  w.sc1w=(const float*)d_in[5];  w.sc1b=(const float*)d_in[6];
  w.rc0w=(const float*)d_in[7];  w.rc0b=(const float*)d_in[8];
  w.rc1w=(const float*)d_in[9];  w.rc1b=(const float*)d_in[10];
  w.rc2w=(const float*)d_in[11]; w.rc2b=(const float*)d_in[12];
  w.at0w=(const float*)d_in[13]; w.at0b=(const float*)d_in[14];
  w.at1w=(const float*)d_in[15]; w.at1b=(const float*)d_in[16];
  w.at2w=(const float*)d_in[17]; w.at2b=(const float*)d_in[18];
  w.af0w=(const float*)d_in[19]; w.af0b=(const float*)d_in[20];
  w.af1w=(const float*)d_in[21]; w.af1b=(const float*)d_in[22];
  w.af2w=(const float*)d_in[23]; w.af2b=(const float*)d_in[24];
  w.o0w =(const float*)d_in[25]; w.o0b =(const float*)d_in[26];
  w.o1w =(const float*)d_in[27]; w.o1b =(const float*)d_in[28];

  float* out = (float*)d_out;
  float* out_roll    = out;                              // (16,8,128,4)
  float* out_present = out + NB*NROLL*NOBJ*4;            // (16,4,128,4)

  float* ws = (float*)d_ws;
  size_t off = 0;
  auto alloc = [&](size_t n){ float* p = ws + off; off += n; return p; };
  float* S[2]    = { alloc(NB*NOBJ*32),   alloc(NB*NOBJ*32) };
  float* SD[2]   = { alloc(NB*NOBJ*32),   alloc(NB*NOBJ*32) };
  float* P1R[2]  = { alloc(NB*NOBJ*64),   alloc(NB*NOBJ*64) };
  float* P1A[2]  = { alloc(NB*NOBJ*64),   alloc(NB*NOBJ*64) };
  float* P2AR[2] = { alloc(NB*64*NOBJ*2), alloc(NB*64*NOBJ*2) };
  float* PX[2]   = { alloc(NB*NOBJ),      alloc(NB*NOBJ) };
  float* PY[2]   = { alloc(NB*NOBJ),      alloc(NB*NOBJ) };
  uint4* fragbuf = (uint4*)alloc(512 * 4);               // 8 KB packed B-frags
  (void)ws_size; (void)in_sizes; (void)n_in; (void)out_size;

  hipLaunchKernelGGL(pack_kernel, dim3(1), dim3(512), 0, stream,
                     w.at1w, w.rc1w, fragbuf);
  hipLaunchKernelGGL(encode_kernel, dim3(NB*4), dim3(NOBJ), 0, stream,
                     x, sew, seb, out_present, S[0]);
  hipLaunchKernelGGL(project_kernel, dim3(NB*NOBJ), dim3(64), 0, stream,
                     S[0], w, SD[0], P1R[0], P1A[0], P2AR[0], PX[0], PY[0]);

  for (int t = 0; t < NROLL; t++) {
    int a = t & 1, oo = 1 - a;
    hipLaunchKernelGGL(step_kernel, dim3(NB*NOBJ/2), dim3(256), 0, stream,
                       S[a], SD[a], P1R[a], P1A[a], P2AR[a], PX[a], PY[a],
                       S[oo], SD[oo], P1R[oo], P1A[oo], P2AR[oo], PX[oo], PY[oo],
                       fragbuf, w, out_roll, t);
  }
}

// Round 11
// 389.858 us; speedup vs baseline: 3.8531x; 1.0364x over previous
//
#include <hip/hip_runtime.h>
#include <math.h>

#define NB 16
#define NOBJ 128
#define NROLL 8
#define C2F 2.8853900817779268f   // 2*log2(e)

typedef short bfrag __attribute__((ext_vector_type(8)));   // 8 bf16 (4 VGPR)
typedef float f4t  __attribute__((ext_vector_type(4)));    // MFMA acc
typedef float f2   __attribute__((ext_vector_type(2)));    // packed fp32

struct W {
  const float *rc0w,*rc0b,*rc1w,*rc1b,*rc2w,*rc2b;
  const float *at0w,*at0b,*at1w,*at1b,*at2w,*at2b;
  const float *af0w,*af0b,*af1w,*af1b,*af2w,*af2b;
  const float *o0w,*o0b,*o1w,*o1b;
  const float *sc0w,*sc0b,*sc1w,*sc1b;
};

// tanh for PRE-SCALED input xs = x*2*log2e: 1 - 2/(2^xs + 1)   (4 inst)
__device__ __forceinline__ float tanh4(float xs){
  float e = exp2f(xs);
  return fmaf(__builtin_amdgcn_rcpf(e + 1.f), -2.f, 1.f);
}
// unscaled-input tanh (tail GEMVs)
__device__ __forceinline__ float fast_tanh(float x){
  return tanh4(x * C2F);
}

// fp32 -> bf16 round-to-nearest-even (init kernel only)
__device__ __forceinline__ unsigned f2bf(float f){
  unsigned u = __float_as_uint(f);
  u = u + 0x7fffu + ((u >> 16) & 1u);
  return u >> 16;
}

// pack two fp32 -> one dword of 2 bf16 (RNE) via the HW packer
__device__ __forceinline__ unsigned cvt_pk_bf16(float lo, float hi){
  unsigned r;
  asm("v_cvt_pk_bf16_f32 %0, %1, %2" : "=v"(r) : "v"(lo), "v"(hi));
  return r;
}

// ---------------------------------------------------------------------------
// init: pre-pack at1w (SCALED by C2F) / rc1w (unscaled) into per-lane MFMA
// B-fragment layout; also emit geoAs = at0w geo rows * C2F.
// ---------------------------------------------------------------------------
__global__ __launch_bounds__(512)
void pack_kernel(const float* __restrict__ at1w, const float* __restrict__ rc1w,
                 const float* __restrict__ at0w,
                 uint4* __restrict__ fragbuf, float* __restrict__ geoAs)
{
  int t = threadIdx.x;             // 0..511
  int lane = t & 63, kt = (t>>6)&1, nt = (t>>7)&1, path = t>>8;
  const float* src = path ? rc1w : at1w;
  float sc = path ? 1.f : C2F;
  int c16 = lane & 15, qg = lane >> 4;
  unsigned r[4];
  #pragma unroll
  for (int e2 = 0; e2 < 4; e2++){
    int k0 = kt*32 + qg*8 + e2*2;
    unsigned lo = f2bf(src[k0*32     + nt*16 + c16] * sc);
    unsigned hi = f2bf(src[(k0+1)*32 + nt*16 + c16] * sc);
    r[e2] = lo | (hi << 16);
  }
  uint4 v; v.x=r[0]; v.y=r[1]; v.z=r[2]; v.w=r[3];
  fragbuf[((path*2+nt)*2+kt)*64 + lane] = v;
  if (t < 192) geoAs[t] = at0w[64*64 + t] * C2F;
}

// ---------------------------------------------------------------------------
__global__ __launch_bounds__(128)
void encode_kernel(const float* __restrict__ x, const float* __restrict__ sew,
                   const float* __restrict__ seb, float* __restrict__ present,
                   float* __restrict__ S0)
{
  int bt = blockIdx.x;        // b*4 + t
  int o  = threadIdx.x;       // 0..127
  const float* xv = x + (size_t)(bt * NOBJ + o) * 4;
  float x0 = xv[0], x1 = xv[1], x2 = xv[2], x3 = xv[3];
  float* pr = present + (size_t)(bt * NOBJ + o) * 4;
  pr[0] = x0; pr[1] = x1; pr[2] = x2; pr[3] = x3;
  int t = bt & 3, b = bt >> 2;
  if (t == 3) {
    float* s = S0 + (size_t)(b * NOBJ + o) * 32;
    s[0] = x0; s[1] = x1; s[2] = x2; s[3] = x3;
    #pragma unroll
    for (int k = 4; k < 32; k++)
      s[k] = seb[k] + x0*sew[k] + x1*sew[32+k] + x2*sew[64+k] + x3*sew[96+k];
  }
}

// ---------------------------------------------------------------------------
// per-object projections.  P1A / P2AR.x are emitted PRE-SCALED by C2F.
// ---------------------------------------------------------------------------
__device__ void project_body(int pt, int bo, const float* __restrict__ s_sh,
                             float* __restrict__ h_sh, const W& w,
                             float* __restrict__ SD,
                             float* __restrict__ P1R, float* __restrict__ P1A,
                             float* __restrict__ P2AR,
                             float* __restrict__ PX, float* __restrict__ PY)
{
  int b = bo >> 7, o = bo & 127;
  if (pt < 64) {
    float a1r = w.rc0b[pt], a2r = 0.f, a1a = w.at0b[pt], a2a = 0.f;
    #pragma unroll
    for (int c = 0; c < 32; c++) {
      float sv = s_sh[c];
      a1r += sv * w.rc0w[c*64 + pt];
      a2r += sv * w.rc0w[(32+c)*64 + pt];
      a1a += sv * w.at0w[c*64 + pt];
      a2a += sv * w.at0w[(32+c)*64 + pt];
    }
    P1R[(size_t)bo*64 + pt] = a1r;
    P1A[(size_t)bo*64 + pt] = a1a * C2F;
    float2 pp; pp.x = a2a * C2F; pp.y = a2r;
    ((float2*)P2AR)[(size_t)(b*64 + pt)*NOBJ + o] = pp;
  }
  if (pt < 32) {
    float acc = w.sc0b[pt];
    #pragma unroll
    for (int c = 0; c < 32; c++) acc += s_sh[c] * w.sc0w[c*32 + pt];
    h_sh[pt] = fmaxf(acc, 0.f);
  }
  __syncthreads();
  if (pt < 32) {
    float acc = w.sc1b[pt] + h_sh[pt];
    #pragma unroll
    for (int c = 0; c < 32; c++) acc += h_sh[c] * w.sc1w[c*32 + pt];
    SD[(size_t)bo*32 + pt] = acc;
  }
  if (pt == 0) { PX[bo] = s_sh[0]; PY[bo] = s_sh[1]; }
}

__global__ __launch_bounds__(64)
void project_kernel(const float* __restrict__ S, W w,
                    float* SD, float* P1R, float* P1A,
                    float* P2AR, float* PX, float* PY)
{
  __shared__ float s_sh[32], h_sh[32];
  int bo = blockIdx.x, tid = threadIdx.x;
  if (tid < 32) s_sh[tid] = S[(size_t)bo*32 + tid];
  __syncthreads();
  project_body(tid, bo, s_sh, h_sh, w, SD, P1R, P1A, P2AR, PX, PY);
}

// GEMM pass over one object's 128x64 bf16 swizzled tile.
#define GEMM_PASS(TBASE, BF, COUT) do {                                       \
  _Pragma("unroll")                                                           \
  for (int mt = 0; mt < 4; mt++){                                             \
    int jr = (wv2<<6) + (mt<<4) + c16;                                        \
    const char* rb = (const char*)(TBASE) + (jr<<7);                          \
    bfrag a0 = *((const bfrag*)(rb + (((qg  ) ^ (jr&7))<<4)));                \
    bfrag a1 = *((const bfrag*)(rb + (((4+qg) ^ (jr&7))<<4)));                \
    _Pragma("unroll")                                                         \
    for (int nt = 0; nt < 2; nt++){                                           \
      COUT[mt][nt] = __builtin_amdgcn_mfma_f32_16x16x32_bf16(a0, BF[nt][0], COUT[mt][nt], 0,0,0); \
      COUT[mt][nt] = __builtin_amdgcn_mfma_f32_16x16x32_bf16(a1, BF[nt][1], COUT[mt][nt], 0,0,0); \
    }                                                                         \
  }                                                                           \
} while(0)

// ---------------------------------------------------------------------------
// one rollout step.  block = (b, object-pair), 256 threads (4 waves).
// 32 KB LDS (two 16 KB tiles); tail scratch aliased into tile0 after GEMM2.
// Prep uses packed-f32 (v_pk_fma) and 4-inst scaled tanh.
// ---------------------------------------------------------------------------
__global__ __launch_bounds__(256)
void step_kernel(const float* __restrict__ S_in,  const float* __restrict__ SD_in,
                 const float* __restrict__ P1R_in, const float* __restrict__ P1A_in,
                 const float* __restrict__ P2AR_in,
                 const float* __restrict__ PX_in,  const float* __restrict__ PY_in,
                 float* __restrict__ S_out, float* __restrict__ SD_out,
                 float* __restrict__ P1R_out, float* __restrict__ P1A_out,
                 float* __restrict__ P2AR_out,
                 float* __restrict__ PX_out, float* __restrict__ PY_out,
                 const uint4* __restrict__ fragbuf, const float* __restrict__ geoAs,
                 W w, float* __restrict__ out_roll, int tstep)
{
  __shared__ __align__(16) float smem[8192];   // EXACTLY 32 KB
  float* qb_base = smem;          // aliased into tile0 after GEMM2
  float* vb_base = smem + 512;

  int tid = threadIdx.x;
  int g   = tid >> 7;             // k-half for prep
  int lt  = tid & 127;            // j
  int w4  = tid >> 6;             // wave 0..3
  int obj = w4 >> 1;              // object for GEMM/attv/q phases
  int wv2 = w4 & 1;               // M-half within object
  int l = tid & 63, c16 = l & 15, qg = l >> 4;

  int p = blockIdx.x & 63, b = blockIdx.x >> 6;
  int i0 = 2*p;
  int bi0 = b*NOBJ + i0, bi1 = bi0 + 1;

  char* t0 = (char*)smem;
  char* t1 = (char*)smem + 16384;

  // ---- att B-fragments (pre-packed & pre-scaled; 4 x 16B loads) ----
  bfrag bfA[2][2];
  #pragma unroll
  for (int nt = 0; nt < 2; nt++)
    #pragma unroll
    for (int kt = 0; kt < 2; kt++)
      bfA[nt][kt] = *((const bfrag*)&fragbuf[(nt*2+kt)*64 + l]);

  // ---- geometry for both objects ----
  float px0 = S_in[(size_t)bi0*32 + 0], py0 = S_in[(size_t)bi0*32 + 1];
  float px1 = S_in[(size_t)bi1*32 + 0], py1 = S_in[(size_t)bi1*32 + 1];
  float px_j = PX_in[b*NOBJ + lt], py_j = PY_in[b*NOBJ + lt];
  float dx0 = px0 - px_j, dy0 = py0 - py_j;
  float dx1 = px1 - px_j, dy1 = py1 - py_j;
  float dist0 = sqrtf(dx0*dx0 + dy0*dy0 + 1e-10f);
  float dist1 = sqrtf(dx1*dx1 + dy1*dy1 + 1e-10f);

  const float2* p2p = ((const float2*)P2AR_in) + (size_t)(b*64)*NOBJ + lt;
  const float* p1a0 = P1A_in + (size_t)bi0*64;   // scaled
  const float* p1r0 = P1R_in + (size_t)bi0*64;
  const float* p1a1 = P1A_in + (size_t)bi1*64;   // scaled
  const float* p1r1 = P1R_in + (size_t)bi1*64;
  const float* gR = w.rc0w + 64*64;

  // ---- fused prep: 32 p2p loads -> acts for BOTH objects (packed f32) ----
  unsigned relpk[2][16];
  #pragma unroll
  for (int sl = 0; sl < 4; sl++){
    unsigned aw0[4], aw1[4];
    #pragma unroll
    for (int e2 = 0; e2 < 4; e2++){
      int k0 = g*32 + sl*8 + e2*2;
      float2 pa0 = p2p[(size_t)k0*NOBJ];
      float2 pa1 = p2p[(size_t)(k0+1)*NOBJ];
      f2 pA = {pa0.x, pa1.x};          // scaled att j-halves
      f2 pR = {pa0.y, pa1.y};
      f2 g0 = *(const f2*)&geoAs[k0];      // scaled
      f2 g1 = *(const f2*)&geoAs[64+k0];
      f2 g2 = *(const f2*)&geoAs[128+k0];
      f2 h0 = *(const f2*)&gR[k0];
      f2 h1 = *(const f2*)&gR[64+k0];
      f2 h2 = *(const f2*)&gR[128+k0];
      f2 pA0v = *(const f2*)&p1a0[k0];
      f2 pR0v = *(const f2*)&p1r0[k0];
      f2 pA1v = *(const f2*)&p1a1[k0];
      f2 pR1v = *(const f2*)&p1r1[k0];
      f2 xA0 = pA0v + pA + dist0*g0 + dx0*g1 + dy0*g2;   // scaled pre-act
      f2 xR0 = pR0v + pR + dist0*h0 + dx0*h1 + dy0*h2;
      f2 xA1 = pA1v + pA + dist1*g0 + dx1*g1 + dy1*g2;
      f2 xR1 = pR1v + pR + dist1*h0 + dx1*h1 + dy1*h2;
      aw0[e2] = cvt_pk_bf16(tanh4(xA0.x), tanh4(xA0.y));
      relpk[0][sl*4+e2] = cvt_pk_bf16(fmaxf(xR0.x,0.f), fmaxf(xR0.y,0.f));
      aw1[e2] = cvt_pk_bf16(tanh4(xA1.x), tanh4(xA1.y));
      relpk[1][sl*4+e2] = cvt_pk_bf16(fmaxf(xR1.x,0.f), fmaxf(xR1.y,0.f));
    }
    int s = g*4 + sl;
    unsigned off = (lt<<7) + ((s ^ (lt&7))<<4);
    uint4 pk0; pk0.x=aw0[0]; pk0.y=aw0[1]; pk0.z=aw0[2]; pk0.w=aw0[3];
    uint4 pk1; pk1.x=aw1[0]; pk1.y=aw1[1]; pk1.z=aw1[2]; pk1.w=aw1[3];
    *((uint4*)(t0 + off)) = pk0;
    *((uint4*)(t1 + off)) = pk1;
  }
  __syncthreads();

  // ================= attention GEMMs (waves 0,1: obj0 | 2,3: obj1) ========
  const char* mytile = (const char*)smem + (obj<<14);
  f4t cA[4][2];
  #pragma unroll
  for (int mt = 0; mt < 4; mt++)
    #pragma unroll
    for (int nt = 0; nt < 2; nt++) cA[mt][nt] = (f4t){0.f,0.f,0.f,0.f};
  GEMM_PASS(mytile, bfA, cA);
  __syncthreads();   // tile reads done

  // ---- store rel tiles (overwrite) + attv epilogue (reg-only) ----
  #pragma unroll
  for (int sl = 0; sl < 4; sl++){
    int s = g*4 + sl;
    unsigned off = (lt<<7) + ((s ^ (lt&7))<<4);
    uint4 pk0; pk0.x=relpk[0][sl*4]; pk0.y=relpk[0][sl*4+1];
               pk0.z=relpk[0][sl*4+2]; pk0.w=relpk[0][sl*4+3];
    uint4 pk1; pk1.x=relpk[1][sl*4]; pk1.y=relpk[1][sl*4+1];
               pk1.z=relpk[1][sl*4+2]; pk1.w=relpk[1][sl*4+3];
    *((uint4*)(t0 + off)) = pk0;
    *((uint4*)(t1 + off)) = pk1;
  }

  int i_self = i0 + obj;
  float attv[16];
  {
    float bA0 = w.at1b[c16] * C2F, bA1 = w.at1b[16 + c16] * C2F;
    float w20 = w.at2w[c16], w21 = w.at2w[16 + c16];
    float a2b = w.at2b[0];
    #pragma unroll
    for (int mt = 0; mt < 4; mt++)
      #pragma unroll
      for (int reg = 0; reg < 4; reg++) {
        float s = tanh4(cA[mt][0][reg] + bA0) * w20
                + tanh4(cA[mt][1][reg] + bA1) * w21;
        s += __shfl_xor(s, 1); s += __shfl_xor(s, 2);
        s += __shfl_xor(s, 4); s += __shfl_xor(s, 8);
        int jj = wv2*64 + mt*16 + qg*4 + reg;
        attv[mt*4 + reg] = (jj == i_self) ? 0.f : __expf(s + a2b);
      }
  }

  // ---- rel B-fragments (loaded late) ----
  bfrag bfR[2][2];
  #pragma unroll
  for (int nt = 0; nt < 2; nt++)
    #pragma unroll
    for (int kt = 0; kt < 2; kt++)
      bfR[nt][kt] = *((const bfrag*)&fragbuf[(4 + nt*2+kt)*64 + l]);
  __syncthreads();   // rel tiles ready

  // ================= relation GEMMs =================
  f4t cR[4][2];
  #pragma unroll
  for (int mt = 0; mt < 4; mt++)
    #pragma unroll
    for (int nt = 0; nt < 2; nt++) cR[mt][nt] = (f4t){0.f,0.f,0.f,0.f};
  GEMM_PASS(mytile, bfR, cR);

  // epilogue: q = sum_j att_j * relu(r2pre_j), A = sum_j att_j  (regs only)
  float q0 = 0.f, q1 = 0.f, Ap = 0.f;
  {
    float bR0 = w.rc1b[c16], bR1 = w.rc1b[16 + c16];
    #pragma unroll
    for (int mt = 0; mt < 4; mt++)
      #pragma unroll
      for (int reg = 0; reg < 4; reg++) {
        float av = attv[mt*4 + reg]; Ap += av;
        q0 += av * fmaxf(cR[mt][0][reg] + bR0, 0.f);
        q1 += av * fmaxf(cR[mt][1][reg] + bR1, 0.f);
      }
    q0 += __shfl_xor(q0, 16); q0 += __shfl_xor(q0, 32);
    q1 += __shfl_xor(q1, 16); q1 += __shfl_xor(q1, 32);
    Ap += __shfl_xor(Ap, 16); Ap += __shfl_xor(Ap, 32);
  }
  __syncthreads();   // ALL GEMM2 tile reads done -> safe to overwrite tile0
  {
    float* qb = qb_base + obj*66;
    if (l < 16) { qb[wv2*33 + l] = q0; qb[wv2*33 + 16 + l] = q1; }
    if (l == 0) qb[wv2*33 + 32] = Ap;
  }
  __syncthreads();

  // ---- per-object tails: og=0 on wave0, og=1 on wave2; 2-way k-split ----
  int og = tid >> 7, tl = tid & 127;
  int bio = bi0 + og;
  float* qbo  = qb_base + og*66;
  float* v0_sh = vb_base + og*160;
  float* v1_sh = v0_sh + 32;
  float* v2_sh = v0_sh + 64;
  float* snew_sh = v0_sh + 96;
  float* h_sh = v0_sh + 128;
  int outc = tl & 31, half = (tl >> 5) & 1;

  if (tl < 32) v2_sh[tl] = qbo[tl] + qbo[33 + tl];     // q combined
  __syncthreads();
  if (tl < 64) {                        // dyn = SD + q@rc2w + A*rc2b + q
    float acc = 0.f;
    #pragma unroll
    for (int k = 0; k < 16; k++) acc += v2_sh[half*16+k] * w.rc2w[(half*16+k)*32 + outc];
    acc += __shfl_xor(acc, 32);
    if (!half) {
      float A = qbo[32] + qbo[65];
      v0_sh[outc] = SD_in[(size_t)bio*32 + outc] + A * w.rc2b[outc] + v2_sh[outc] + acc;
    }
  }
  __syncthreads();
  if (tl < 64) {                        // aff1
    float acc = 0.f;
    #pragma unroll
    for (int k = 0; k < 16; k++) acc += v0_sh[half*16+k] * w.af0w[(half*16+k)*32 + outc];
    acc += __shfl_xor(acc, 32);
    if (!half) v1_sh[outc] = fast_tanh(acc + w.af0b[outc]);
  }
  __syncthreads();
  if (tl < 64) {                        // aff2
    float acc = 0.f;
    #pragma unroll
    for (int k = 0; k < 16; k++) acc += v1_sh[half*16+k] * w.af1w[(half*16+k)*32 + outc];
    acc += __shfl_xor(acc, 32);
    if (!half) v2_sh[outc] = fast_tanh(acc + w.af1b[outc]) + v1_sh[outc];
  }
  __syncthreads();
  if (tl < 64) {                        // aff3
    float acc = 0.f;
    #pragma unroll
    for (int k = 0; k < 16; k++) acc += v2_sh[half*16+k] * w.af2w[(half*16+k)*32 + outc];
    acc += __shfl_xor(acc, 32);
    if (!half) v0_sh[outc] = acc + w.af2b[outc];
  }
  __syncthreads();
  if (tl < 64) {                        // out1 = tanh([aff3,s]@o0+b), K=64
    float acc = 0.f;
    #pragma unroll
    for (int k = 0; k < 32; k++) {
      float src = half ? S_in[(size_t)bio*32 + k] : v0_sh[k];
      acc += src * w.o0w[(half*32+k)*32 + outc];
    }
    acc += __shfl_xor(acc, 32);
    if (!half) v1_sh[outc] = fast_tanh(acc + w.o0b[outc]);
  }
  __syncthreads();
  if (tl < 64) {                        // res = out1@o1 + b + out1 (+s[:2])
    float acc = 0.f;
    #pragma unroll
    for (int k = 0; k < 16; k++) acc += v1_sh[half*16+k] * w.o1w[(half*16+k)*32 + outc];
    acc += __shfl_xor(acc, 32);
    if (!half) {
      acc += w.o1b[outc] + v1_sh[outc];
      if (outc < 2) acc += S_in[(size_t)bio*32 + outc];
      snew_sh[outc] = acc;
      S_out[(size_t)bio*32 + outc] = acc;
      if (outc < 4)
        out_roll[(size_t)((b*NROLL + tstep)*NOBJ + (i0 + og))*4 + outc] = acc;
    }
  }
  __syncthreads();

  // ---- fused projections of the NEW states (both objects in parallel) ----
  project_body(tl, bio, snew_sh, h_sh, w,
               SD_out, P1R_out, P1A_out, P2AR_out, PX_out, PY_out);
}

// ---------------------------------------------------------------------------
extern "C" void kernel_launch(void* const* d_in, const int* in_sizes, int n_in,
                              void* d_out, int out_size, void* d_ws, size_t ws_size,
                              hipStream_t stream)
{
  const float* x    = (const float*)d_in[0];
  const float* sew  = (const float*)d_in[1];
  const float* seb  = (const float*)d_in[2];
  W w;
  w.sc0w=(const float*)d_in[3];  w.sc0b=(const float*)d_in[4];
  w.sc1w=(const float*)d_in[5];  w.sc1b=(const float*)d_in[6];
  w.rc0w=(const float*)d_in[7];  w.rc0b=(const float*)d_in[8];
  w.rc1w=(const float*)d_in[9];  w.rc1b=(const float*)d_in[10];
  w.rc2w=(const float*)d_in[11]; w.rc2b=(const float*)d_in[12];
  w.at0w=(const float*)d_in[13]; w.at0b=(const float*)d_in[14];
  w.at1w=(const float*)d_in[15]; w.at1b=(const float*)d_in[16];
  w.at2w=(const float*)d_in[17]; w.at2b=(const float*)d_in[18];
  w.af0w=(const float*)d_in[19]; w.af0b=(const float*)d_in[20];
  w.af1w=(const float*)d_in[21]; w.af1b=(const float*)d_in[22];
  w.af2w=(const float*)d_in[23]; w.af2b=(const float*)d_in[24];
  w.o0w =(const float*)d_in[25]; w.o0b =(const float*)d_in[26];
  w.o1w =(const float*)d_in[27]; w.o1b =(const float*)d_in[28];

  float* out = (float*)d_out;
  float* out_roll    = out;                              // (16,8,128,4)
  float* out_present = out + NB*NROLL*NOBJ*4;            // (16,4,128,4)

  float* ws = (float*)d_ws;
  size_t off = 0;
  auto alloc = [&](size_t n){ float* p = ws + off; off += n; return p; };
  float* S[2]    = { alloc(NB*NOBJ*32),   alloc(NB*NOBJ*32) };
  float* SD[2]   = { alloc(NB*NOBJ*32),   alloc(NB*NOBJ*32) };
  float* P1R[2]  = { alloc(NB*NOBJ*64),   alloc(NB*NOBJ*64) };
  float* P1A[2]  = { alloc(NB*NOBJ*64),   alloc(NB*NOBJ*64) };
  float* P2AR[2] = { alloc(NB*64*NOBJ*2), alloc(NB*64*NOBJ*2) };
  float* PX[2]   = { alloc(NB*NOBJ),      alloc(NB*NOBJ) };
  float* PY[2]   = { alloc(NB*NOBJ),      alloc(NB*NOBJ) };
  uint4* fragbuf = (uint4*)alloc(512 * 4);               // 8 KB packed B-frags
  float* geoAs   = alloc(192);                           // scaled att geo rows
  (void)ws_size; (void)in_sizes; (void)n_in; (void)out_size;

  hipLaunchKernelGGL(pack_kernel, dim3(1), dim3(512), 0, stream,
                     w.at1w, w.rc1w, w.at0w, fragbuf, geoAs);
  hipLaunchKernelGGL(encode_kernel, dim3(NB*4), dim3(NOBJ), 0, stream,
                     x, sew, seb, out_present, S[0]);
  hipLaunchKernelGGL(project_kernel, dim3(NB*NOBJ), dim3(64), 0, stream,
                     S[0], w, SD[0], P1R[0], P1A[0], P2AR[0], PX[0], PY[0]);

  for (int t = 0; t < NROLL; t++) {
    int a = t & 1, oo = 1 - a;
    hipLaunchKernelGGL(step_kernel, dim3(NB*NOBJ/2), dim3(256), 0, stream,
                       S[a], SD[a], P1R[a], P1A[a], P2AR[a], PX[a], PY[a],
                       S[oo], SD[oo], P1R[oo], P1A[oo], P2AR[oo], PX[oo], PY[oo],
                       fragbuf, geoAs, w, out_roll, t);
  }
}

// Round 13
// 381.789 us; speedup vs baseline: 3.9345x; 1.0211x over previous
//
#include <hip/hip_runtime.h>
#include <math.h>

#define NB 16
#define NOBJ 128
#define NROLL 8
#define C2F 2.8853900817779268f   // 2*log2(e)

typedef short bfrag __attribute__((ext_vector_type(8)));   // 8 bf16 (4 VGPR)
typedef float f4t  __attribute__((ext_vector_type(4)));    // MFMA acc
typedef float f2   __attribute__((ext_vector_type(2)));    // packed fp32

struct W {
  const float *rc0w,*rc0b,*rc1w,*rc1b,*rc2w,*rc2b;
  const float *at0w,*at0b,*at1w,*at1b,*at2w,*at2b;
  const float *af0w,*af0b,*af1w,*af1b,*af2w,*af2b;
  const float *o0w,*o0b,*o1w,*o1b;
  const float *sc0w,*sc0b,*sc1w,*sc1b;
};

// tanh for PRE-SCALED input xs = x*2*log2e: 1 - 2/(2^xs + 1)   (4 inst)
__device__ __forceinline__ float tanh4(float xs){
  float e = exp2f(xs);
  return fmaf(__builtin_amdgcn_rcpf(e + 1.f), -2.f, 1.f);
}
__device__ __forceinline__ float fast_tanh(float x){ return tanh4(x * C2F); }

// fp32 -> bf16 RNE (init kernel only)
__device__ __forceinline__ unsigned f2bf(float f){
  unsigned u = __float_as_uint(f);
  u = u + 0x7fffu + ((u >> 16) & 1u);
  return u >> 16;
}
// pack two fp32 -> one dword of 2 bf16 (RNE) via the HW packer
__device__ __forceinline__ unsigned cvt_pk_bf16(float lo, float hi){
  unsigned r;
  asm("v_cvt_pk_bf16_f32 %0, %1, %2" : "=v"(r) : "v"(lo), "v"(hi));
  return r;
}

// ---------------------------------------------------------------------------
// per-object projections.  P1A / P2AR.x emitted PRE-SCALED by C2F.
// Internal barrier must be reached by ALL block threads.
// ---------------------------------------------------------------------------
__device__ void project_body(int pt, int bo, const float* __restrict__ s_sh,
                             float* __restrict__ h_sh, const W& w,
                             float* __restrict__ SD,
                             float* __restrict__ P1R, float* __restrict__ P1A,
                             float* __restrict__ P2AR,
                             float* __restrict__ PX, float* __restrict__ PY)
{
  int b = bo >> 7, o = bo & 127;
  if (pt < 64) {
    float a1r = w.rc0b[pt], a2r = 0.f, a1a = w.at0b[pt], a2a = 0.f;
    #pragma unroll
    for (int c = 0; c < 32; c++) {
      float sv = s_sh[c];
      a1r += sv * w.rc0w[c*64 + pt];
      a2r += sv * w.rc0w[(32+c)*64 + pt];
      a1a += sv * w.at0w[c*64 + pt];
      a2a += sv * w.at0w[(32+c)*64 + pt];
    }
    P1R[(size_t)bo*64 + pt] = a1r;
    P1A[(size_t)bo*64 + pt] = a1a * C2F;
    float2 pp; pp.x = a2a * C2F; pp.y = a2r;
    ((float2*)P2AR)[(size_t)(b*64 + pt)*NOBJ + o] = pp;
  }
  if (pt < 32) {
    float acc = w.sc0b[pt];
    #pragma unroll
    for (int c = 0; c < 32; c++) acc += s_sh[c] * w.sc0w[c*32 + pt];
    h_sh[pt] = fmaxf(acc, 0.f);
  }
  __syncthreads();
  if (pt < 32) {
    float acc = w.sc1b[pt] + h_sh[pt];
    #pragma unroll
    for (int c = 0; c < 32; c++) acc += h_sh[c] * w.sc1w[c*32 + pt];
    SD[(size_t)bo*32 + pt] = acc;
  }
  if (pt == 0) { PX[bo] = s_sh[0]; PY[bo] = s_sh[1]; }
}

// ---------------------------------------------------------------------------
// fused init: present copy + weight pack (blocks 0,1) + S0 + projections.
// All dependencies are block-local.  grid = 1024 x 256.
// ---------------------------------------------------------------------------
__global__ __launch_bounds__(256)
void init_kernel(const float* __restrict__ x, const float* __restrict__ sew,
                 const float* __restrict__ seb, W w,
                 float* __restrict__ present, float* __restrict__ S0,
                 float* SD, float* P1R, float* P1A, float* P2AR,
                 float* PX, float* PY,
                 uint4* __restrict__ fragbuf, float* __restrict__ geoAs)
{
  __shared__ float sbuf[2][160];
  int tid = threadIdx.x, bid = blockIdx.x;

  // ---- A: coalesced present copy (first 128 blocks cover 32768 floats) ----
  {
    int idx = bid*256 + tid;
    if (idx < NB*4*NOBJ*4) present[idx] = x[idx];
  }

  // ---- B: weight pack + scaled geo rows (blocks 0,1) ----
  if (bid < 2) {
    int t5 = bid*256 + tid;       // 0..511
    int lane = t5 & 63, kt = (t5>>6)&1, nt = (t5>>7)&1, path = t5>>8;
    const float* src = path ? w.rc1w : w.at1w;
    float sc = path ? 1.f : C2F;
    int c16p = lane & 15, qgp = lane >> 4;
    unsigned r[4];
    #pragma unroll
    for (int e2 = 0; e2 < 4; e2++){
      int k0 = kt*32 + qgp*8 + e2*2;
      unsigned lo = f2bf(src[k0*32     + nt*16 + c16p] * sc);
      unsigned hi = f2bf(src[(k0+1)*32 + nt*16 + c16p] * sc);
      r[e2] = lo | (hi << 16);
    }
    uint4 v; v.x=r[0]; v.y=r[1]; v.z=r[2]; v.w=r[3];
    fragbuf[((path*2+nt)*2+kt)*64 + lane] = v;
    if (t5 < 192) geoAs[t5] = w.at0w[64*64 + t5] * C2F;
  }

  // ---- C: S0 (encode, t=3 slice) + projection for this block's 2 objects --
  int og = tid >> 7, tl = tid & 127;
  int bo = bid*2 + og, o = bo & 127, b = bo >> 7;
  float* s_sh = sbuf[og];
  float* h_sh = s_sh + 128;
  const float* xr = x + (size_t)((b*4 + 3)*NOBJ + o)*4;
  if (tl < 32) {
    float v;
    if (tl < 4) v = xr[tl];
    else v = seb[tl] + xr[0]*sew[tl] + xr[1]*sew[32+tl]
           + xr[2]*sew[64+tl] + xr[3]*sew[96+tl];
    s_sh[tl] = v;
    S0[(size_t)bo*32 + tl] = v;
  }
  __syncthreads();
  project_body(tl, bo, s_sh, h_sh, w, SD, P1R, P1A, P2AR, PX, PY);
}

// GEMM pass over one object's 128x64 bf16 swizzled tile.
#define GEMM_PASS(TBASE, BF, COUT) do {                                       \
  _Pragma("unroll")                                                           \
  for (int mt = 0; mt < 4; mt++){                                             \
    int jr = (wv2<<6) + (mt<<4) + c16;                                        \
    const char* rb = (const char*)(TBASE) + (jr<<7);                          \
    bfrag a0 = *((const bfrag*)(rb + (((qg  ) ^ (jr&7))<<4)));                \
    bfrag a1 = *((const bfrag*)(rb + (((4+qg) ^ (jr&7))<<4)));                \
    _Pragma("unroll")                                                         \
    for (int nt = 0; nt < 2; nt++){                                           \
      COUT[mt][nt] = __builtin_amdgcn_mfma_f32_16x16x32_bf16(a0, BF[nt][0], COUT[mt][nt], 0,0,0); \
      COUT[mt][nt] = __builtin_amdgcn_mfma_f32_16x16x32_bf16(a1, BF[nt][1], COUT[mt][nt], 0,0,0); \
    }                                                                         \
  }                                                                           \
} while(0)

// ---------------------------------------------------------------------------
// one rollout step (identical to round-11's passing kernel).
// block = (b, object-pair), 256 threads (4 waves); 32 KB LDS.
// ---------------------------------------------------------------------------
__global__ __launch_bounds__(256)
void step_kernel(const float* __restrict__ S_in,  const float* __restrict__ SD_in,
                 const float* __restrict__ P1R_in, const float* __restrict__ P1A_in,
                 const float* __restrict__ P2AR_in,
                 const float* __restrict__ PX_in,  const float* __restrict__ PY_in,
                 float* __restrict__ S_out, float* __restrict__ SD_out,
                 float* __restrict__ P1R_out, float* __restrict__ P1A_out,
                 float* __restrict__ P2AR_out,
                 float* __restrict__ PX_out, float* __restrict__ PY_out,
                 const uint4* __restrict__ fragbuf, const float* __restrict__ geoAs,
                 W w, float* __restrict__ out_roll, int tstep)
{
  __shared__ __align__(16) float smem[8192];   // EXACTLY 32 KB
  float* qb_base = smem;          // aliased into tile0 after GEMM2
  float* vb_base = smem + 512;

  int tid = threadIdx.x;
  int g   = tid >> 7;             // k-half for prep
  int lt  = tid & 127;            // j
  int w4  = tid >> 6;             // wave 0..3
  int obj = w4 >> 1;              // object for GEMM/attv/q phases
  int wv2 = w4 & 1;               // M-half within object
  int l = tid & 63, c16 = l & 15, qg = l >> 4;

  int p = blockIdx.x & 63, b = blockIdx.x >> 6;
  int i0 = 2*p;
  int bi0 = b*NOBJ + i0, bi1 = bi0 + 1;

  char* t0 = (char*)smem;
  char* t1 = (char*)smem + 16384;

  // ---- att B-fragments (pre-packed & pre-scaled; 4 x 16B loads) ----
  bfrag bfA[2][2];
  #pragma unroll
  for (int nt = 0; nt < 2; nt++)
    #pragma unroll
    for (int kt = 0; kt < 2; kt++)
      bfA[nt][kt] = *((const bfrag*)&fragbuf[(nt*2+kt)*64 + l]);

  // ---- geometry for both objects ----
  float px0 = S_in[(size_t)bi0*32 + 0], py0 = S_in[(size_t)bi0*32 + 1];
  float px1 = S_in[(size_t)bi1*32 + 0], py1 = S_in[(size_t)bi1*32 + 1];
  float px_j = PX_in[b*NOBJ + lt], py_j = PY_in[b*NOBJ + lt];
  float dx0 = px0 - px_j, dy0 = py0 - py_j;
  float dx1 = px1 - px_j, dy1 = py1 - py_j;
  float dist0 = sqrtf(dx0*dx0 + dy0*dy0 + 1e-10f);
  float dist1 = sqrtf(dx1*dx1 + dy1*dy1 + 1e-10f);

  const float2* p2p = ((const float2*)P2AR_in) + (size_t)(b*64)*NOBJ + lt;
  const float* p1a0 = P1A_in + (size_t)bi0*64;   // scaled
  const float* p1r0 = P1R_in + (size_t)bi0*64;
  const float* p1a1 = P1A_in + (size_t)bi1*64;   // scaled
  const float* p1r1 = P1R_in + (size_t)bi1*64;
  const float* gR = w.rc0w + 64*64;

  // ---- fused prep: 32 p2p loads -> acts for BOTH objects (packed f32) ----
  unsigned relpk[2][16];
  #pragma unroll
  for (int sl = 0; sl < 4; sl++){
    unsigned aw0[4], aw1[4];
    #pragma unroll
    for (int e2 = 0; e2 < 4; e2++){
      int k0 = g*32 + sl*8 + e2*2;
      float2 pa0 = p2p[(size_t)k0*NOBJ];
      float2 pa1 = p2p[(size_t)(k0+1)*NOBJ];
      f2 pA = {pa0.x, pa1.x};
      f2 pR = {pa0.y, pa1.y};
      f2 g0 = *(const f2*)&geoAs[k0];
      f2 g1 = *(const f2*)&geoAs[64+k0];
      f2 g2 = *(const f2*)&geoAs[128+k0];
      f2 h0 = *(const f2*)&gR[k0];
      f2 h1 = *(const f2*)&gR[64+k0];
      f2 h2 = *(const f2*)&gR[128+k0];
      f2 pA0v = *(const f2*)&p1a0[k0];
      f2 pR0v = *(const f2*)&p1r0[k0];
      f2 pA1v = *(const f2*)&p1a1[k0];
      f2 pR1v = *(const f2*)&p1r1[k0];
      f2 xA0 = pA0v + pA + dist0*g0 + dx0*g1 + dy0*g2;
      f2 xR0 = pR0v + pR + dist0*h0 + dx0*h1 + dy0*h2;
      f2 xA1 = pA1v + pA + dist1*g0 + dx1*g1 + dy1*g2;
      f2 xR1 = pR1v + pR + dist1*h0 + dx1*h1 + dy1*h2;
      aw0[e2] = cvt_pk_bf16(tanh4(xA0.x), tanh4(xA0.y));
      relpk[0][sl*4+e2] = cvt_pk_bf16(fmaxf(xR0.x,0.f), fmaxf(xR0.y,0.f));
      aw1[e2] = cvt_pk_bf16(tanh4(xA1.x), tanh4(xA1.y));
      relpk[1][sl*4+e2] = cvt_pk_bf16(fmaxf(xR1.x,0.f), fmaxf(xR1.y,0.f));
    }
    int s = g*4 + sl;
    unsigned off = (lt<<7) + ((s ^ (lt&7))<<4);
    uint4 pk0; pk0.x=aw0[0]; pk0.y=aw0[1]; pk0.z=aw0[2]; pk0.w=aw0[3];
    uint4 pk1; pk1.x=aw1[0]; pk1.y=aw1[1]; pk1.z=aw1[2]; pk1.w=aw1[3];
    *((uint4*)(t0 + off)) = pk0;
    *((uint4*)(t1 + off)) = pk1;
  }
  __syncthreads();

  // ================= attention GEMMs (waves 0,1: obj0 | 2,3: obj1) ========
  const char* mytile = (const char*)smem + (obj<<14);
  f4t cA[4][2];
  #pragma unroll
  for (int mt = 0; mt < 4; mt++)
    #pragma unroll
    for (int nt = 0; nt < 2; nt++) cA[mt][nt] = (f4t){0.f,0.f,0.f,0.f};
  GEMM_PASS(mytile, bfA, cA);
  __syncthreads();   // tile reads done

  // ---- store rel tiles (overwrite) + attv epilogue (reg-only) ----
  #pragma unroll
  for (int sl = 0; sl < 4; sl++){
    int s = g*4 + sl;
    unsigned off = (lt<<7) + ((s ^ (lt&7))<<4);
    uint4 pk0; pk0.x=relpk[0][sl*4]; pk0.y=relpk[0][sl*4+1];
               pk0.z=relpk[0][sl*4+2]; pk0.w=relpk[0][sl*4+3];
    uint4 pk1; pk1.x=relpk[1][sl*4]; pk1.y=relpk[1][sl*4+1];
               pk1.z=relpk[1][sl*4+2]; pk1.w=relpk[1][sl*4+3];
    *((uint4*)(t0 + off)) = pk0;
    *((uint4*)(t1 + off)) = pk1;
  }

  int i_self = i0 + obj;
  float attv[16];
  {
    float bA0 = w.at1b[c16] * C2F, bA1 = w.at1b[16 + c16] * C2F;
    float w20 = w.at2w[c16], w21 = w.at2w[16 + c16];
    float a2b = w.at2b[0];
    #pragma unroll
    for (int mt = 0; mt < 4; mt++)
      #pragma unroll
      for (int reg = 0; reg < 4; reg++) {
        float s = tanh4(cA[mt][0][reg] + bA0) * w20
                + tanh4(cA[mt][1][reg] + bA1) * w21;
        s += __shfl_xor(s, 1); s += __shfl_xor(s, 2);
        s += __shfl_xor(s, 4); s += __shfl_xor(s, 8);
        int jj = wv2*64 + mt*16 + qg*4 + reg;
        attv[mt*4 + reg] = (jj == i_self) ? 0.f : __expf(s + a2b);
      }
  }

  // ---- rel B-fragments (loaded late) ----
  bfrag bfR[2][2];
  #pragma unroll
  for (int nt = 0; nt < 2; nt++)
    #pragma unroll
    for (int kt = 0; kt < 2; kt++)
      bfR[nt][kt] = *((const bfrag*)&fragbuf[(4 + nt*2+kt)*64 + l]);
  __syncthreads();   // rel tiles ready

  // ================= relation GEMMs =================
  f4t cR[4][2];
  #pragma unroll
  for (int mt = 0; mt < 4; mt++)
    #pragma unroll
    for (int nt = 0; nt < 2; nt++) cR[mt][nt] = (f4t){0.f,0.f,0.f,0.f};
  GEMM_PASS(mytile, bfR, cR);

  // epilogue: q = sum_j att_j * relu(r2pre_j), A = sum_j att_j  (regs only)
  float q0 = 0.f, q1 = 0.f, Ap = 0.f;
  {
    float bR0 = w.rc1b[c16], bR1 = w.rc1b[16 + c16];
    #pragma unroll
    for (int mt = 0; mt < 4; mt++)
      #pragma unroll
      for (int reg = 0; reg < 4; reg++) {
        float av = attv[mt*4 + reg]; Ap += av;
        q0 += av * fmaxf(cR[mt][0][reg] + bR0, 0.f);
        q1 += av * fmaxf(cR[mt][1][reg] + bR1, 0.f);
      }
    q0 += __shfl_xor(q0, 16); q0 += __shfl_xor(q0, 32);
    q1 += __shfl_xor(q1, 16); q1 += __shfl_xor(q1, 32);
    Ap += __shfl_xor(Ap, 16); Ap += __shfl_xor(Ap, 32);
  }
  __syncthreads();   // ALL GEMM2 tile reads done -> safe to overwrite tile0
  {
    float* qb = qb_base + obj*66;
    if (l < 16) { qb[wv2*33 + l] = q0; qb[wv2*33 + 16 + l] = q1; }
    if (l == 0) qb[wv2*33 + 32] = Ap;
  }
  __syncthreads();

  // ---- per-object tails: og=0 on wave0, og=1 on wave2; 2-way k-split ----
  int og = tid >> 7, tl = tid & 127;
  int bio = bi0 + og;
  float* qbo  = qb_base + og*66;
  float* v0_sh = vb_base + og*160;
  float* v1_sh = v0_sh + 32;
  float* v2_sh = v0_sh + 64;
  float* snew_sh = v0_sh + 96;
  float* h_sh = v0_sh + 128;
  int outc = tl & 31, half = (tl >> 5) & 1;

  if (tl < 32) v2_sh[tl] = qbo[tl] + qbo[33 + tl];     // q combined
  __syncthreads();
  if (tl < 64) {                        // dyn = SD + q@rc2w + A*rc2b + q
    float acc = 0.f;
    #pragma unroll
    for (int k = 0; k < 16; k++) acc += v2_sh[half*16+k] * w.rc2w[(half*16+k)*32 + outc];
    acc += __shfl_xor(acc, 32);
    if (!half) {
      float A = qbo[32] + qbo[65];
      v0_sh[outc] = SD_in[(size_t)bio*32 + outc] + A * w.rc2b[outc] + v2_sh[outc] + acc;
    }
  }
  __syncthreads();
  if (tl < 64) {                        // aff1
    float acc = 0.f;
    #pragma unroll
    for (int k = 0; k < 16; k++) acc += v0_sh[half*16+k] * w.af0w[(half*16+k)*32 + outc];
    acc += __shfl_xor(acc, 32);
    if (!half) v1_sh[outc] = fast_tanh(acc + w.af0b[outc]);
  }
  __syncthreads();
  if (tl < 64) {                        // aff2
    float acc = 0.f;
    #pragma unroll
    for (int k = 0; k < 16; k++) acc += v1_sh[half*16+k] * w.af1w[(half*16+k)*32 + outc];
    acc += __shfl_xor(acc, 32);
    if (!half) v2_sh[outc] = fast_tanh(acc + w.af1b[outc]) + v1_sh[outc];
  }
  __syncthreads();
  if (tl < 64) {                        // aff3
    float acc = 0.f;
    #pragma unroll
    for (int k = 0; k < 16; k++) acc += v2_sh[half*16+k] * w.af2w[(half*16+k)*32 + outc];
    acc += __shfl_xor(acc, 32);
    if (!half) v0_sh[outc] = acc + w.af2b[outc];
  }
  __syncthreads();
  if (tl < 64) {                        // out1 = tanh([aff3,s]@o0+b), K=64
    float acc = 0.f;
    #pragma unroll
    for (int k = 0; k < 32; k++) {
      float src = half ? S_in[(size_t)bio*32 + k] : v0_sh[k];
      acc += src * w.o0w[(half*32+k)*32 + outc];
    }
    acc += __shfl_xor(acc, 32);
    if (!half) v1_sh[outc] = fast_tanh(acc + w.o0b[outc]);
  }
  __syncthreads();
  if (tl < 64) {                        // res = out1@o1 + b + out1 (+s[:2])
    float acc = 0.f;
    #pragma unroll
    for (int k = 0; k < 16; k++) acc += v1_sh[half*16+k] * w.o1w[(half*16+k)*32 + outc];
    acc += __shfl_xor(acc, 32);
    if (!half) {
      acc += w.o1b[outc] + v1_sh[outc];
      if (outc < 2) acc += S_in[(size_t)bio*32 + outc];
      snew_sh[outc] = acc;
      S_out[(size_t)bio*32 + outc] = acc;
      if (outc < 4)
        out_roll[(size_t)((b*NROLL + tstep)*NOBJ + (i0 + og))*4 + outc] = acc;
    }
  }
  __syncthreads();

  // ---- fused projections of the NEW states (both objects in parallel) ----
  project_body(tl, bio, snew_sh, h_sh, w,
               SD_out, P1R_out, P1A_out, P2AR_out, PX_out, PY_out);
}

// ---------------------------------------------------------------------------
extern "C" void kernel_launch(void* const* d_in, const int* in_sizes, int n_in,
                              void* d_out, int out_size, void* d_ws, size_t ws_size,
                              hipStream_t stream)
{
  const float* x    = (const float*)d_in[0];
  const float* sew  = (const float*)d_in[1];
  const float* seb  = (const float*)d_in[2];
  W w;
  w.sc0w=(const float*)d_in[3];  w.sc0b=(const float*)d_in[4];
  w.sc1w=(const float*)d_in[5];  w.sc1b=(const float*)d_in[6];
  w.rc0w=(const float*)d_in[7];  w.rc0b=(const float*)d_in[8];
  w.rc1w=(const float*)d_in[9];  w.rc1b=(const float*)d_in[10];
  w.rc2w=(const float*)d_in[11]; w.rc2b=(const float*)d_in[12];
  w.at0w=(const float*)d_in[13]; w.at0b=(const float*)d_in[14];
  w.at1w=(const float*)d_in[15]; w.at1b=(const float*)d_in[16];
  w.at2w=(const float*)d_in[17]; w.at2b=(const float*)d_in[18];
  w.af0w=(const float*)d_in[19]; w.af0b=(const float*)d_in[20];
  w.af1w=(const float*)d_in[21]; w.af1b=(const float*)d_in[22];
  w.af2w=(const float*)d_in[23]; w.af2b=(const float*)d_in[24];
  w.o0w =(const float*)d_in[25]; w.o0b =(const float*)d_in[26];
  w.o1w =(const float*)d_in[27]; w.o1b =(const float*)d_in[28];

  float* out = (float*)d_out;
  float* out_roll    = out;                              // (16,8,128,4)
  float* out_present = out + NB*NROLL*NOBJ*4;            // (16,4,128,4)

  float* ws = (float*)d_ws;
  size_t off = 0;
  auto alloc = [&](size_t n){ float* p = ws + off; off += n; return p; };
  float* S[2]    = { alloc(NB*NOBJ*32),   alloc(NB*NOBJ*32) };
  float* SD[2]   = { alloc(NB*NOBJ*32),   alloc(NB*NOBJ*32) };
  float* P1R[2]  = { alloc(NB*NOBJ*64),   alloc(NB*NOBJ*64) };
  float* P1A[2]  = { alloc(NB*NOBJ*64),   alloc(NB*NOBJ*64) };
  float* P2AR[2] = { alloc(NB*64*NOBJ*2), alloc(NB*64*NOBJ*2) };
  float* PX[2]   = { alloc(NB*NOBJ),      alloc(NB*NOBJ) };
  float* PY[2]   = { alloc(NB*NOBJ),      alloc(NB*NOBJ) };
  uint4* fragbuf = (uint4*)alloc(512 * 4);               // 8 KB packed B-frags
  float* geoAs   = alloc(192);                           // scaled att geo rows
  (void)ws_size; (void)in_sizes; (void)n_in; (void)out_size;

  hipLaunchKernelGGL(init_kernel, dim3(NB*NOBJ/2), dim3(256), 0, stream,
                     x, sew, seb, w, out_present, S[0],
                     SD[0], P1R[0], P1A[0], P2AR[0], PX[0], PY[0],
                     fragbuf, geoAs);

  for (int t = 0; t < NROLL; t++) {
    int a = t & 1, oo = 1 - a;
    hipLaunchKernelGGL(step_kernel, dim3(NB*NOBJ/2), dim3(256), 0, stream,
                       S[a], SD[a], P1R[a], P1A[a], P2AR[a], PX[a], PY[a],
                       S[oo], SD[oo], P1R[oo], P1A[oo], P2AR[oo], PX[oo], PY[oo],
                       fragbuf, geoAs, w, out_roll, t);
  }
}

// Round 14
// 368.141 us; speedup vs baseline: 4.0804x; 1.0371x over previous
//
#include <hip/hip_runtime.h>
#include <math.h>

#define NB 16
#define NOBJ 128
#define NROLL 8
#define C2F 2.8853900817779268f   // 2*log2(e)

typedef short bfrag __attribute__((ext_vector_type(8)));   // 8 bf16 (4 VGPR)
typedef float f4t  __attribute__((ext_vector_type(4)));    // MFMA acc
typedef float f2   __attribute__((ext_vector_type(2)));    // packed fp32

struct W {
  const float *rc0w,*rc0b,*rc1w,*rc1b,*rc2w,*rc2b;
  const float *at0w,*at0b,*at1w,*at1b,*at2w,*at2b;
  const float *af0w,*af0b,*af1w,*af1b,*af2w,*af2b;
  const float *o0w,*o0b,*o1w,*o1b;
  const float *sc0w,*sc0b,*sc1w,*sc1b;
};

// tanh for PRE-SCALED input xs = x*2*log2e: 1 - 2/(2^xs + 1)   (4 inst)
__device__ __forceinline__ float tanh4(float xs){
  float e = exp2f(xs);
  return fmaf(__builtin_amdgcn_rcpf(e + 1.f), -2.f, 1.f);
}
__device__ __forceinline__ float fast_tanh(float x){ return tanh4(x * C2F); }

// fp32 -> bf16 RNE (init kernel only)
__device__ __forceinline__ unsigned f2bf(float f){
  unsigned u = __float_as_uint(f);
  u = u + 0x7fffu + ((u >> 16) & 1u);
  return u >> 16;
}
// pack two fp32 -> one dword of 2 bf16 (RNE) via the HW packer
__device__ __forceinline__ unsigned cvt_pk_bf16(float lo, float hi){
  unsigned r;
  asm("v_cvt_pk_bf16_f32 %0, %1, %2" : "=v"(r) : "v"(lo), "v"(hi));
  return r;
}

// zero-cost compiler scheduling fence (no hardware barrier)
#define WAVE_SYNC() __builtin_amdgcn_wave_barrier()

// ---------------------------------------------------------------------------
// per-object projections.  P1A / P2AR.x emitted PRE-SCALED by C2F.
// WAVE-LOCAL: all LDS communication (s_sh, h_sh) stays within one wave
// (lanes 0..63).  No s_barrier needed — intra-wave LDS is program-ordered.
// ---------------------------------------------------------------------------
__device__ void project_body(int pt, int bo, const float* __restrict__ s_sh,
                             float* __restrict__ h_sh, const W& w,
                             float* __restrict__ SD,
                             float* __restrict__ P1R, float* __restrict__ P1A,
                             float* __restrict__ P2AR,
                             float* __restrict__ PX, float* __restrict__ PY)
{
  int b = bo >> 7, o = bo & 127;
  if (pt < 64) {
    float a1r = w.rc0b[pt], a2r = 0.f, a1a = w.at0b[pt], a2a = 0.f;
    #pragma unroll
    for (int c = 0; c < 32; c++) {
      float sv = s_sh[c];
      a1r += sv * w.rc0w[c*64 + pt];
      a2r += sv * w.rc0w[(32+c)*64 + pt];
      a1a += sv * w.at0w[c*64 + pt];
      a2a += sv * w.at0w[(32+c)*64 + pt];
    }
    P1R[(size_t)bo*64 + pt] = a1r;
    P1A[(size_t)bo*64 + pt] = a1a * C2F;
    float2 pp; pp.x = a2a * C2F; pp.y = a2r;
    ((float2*)P2AR)[(size_t)(b*64 + pt)*NOBJ + o] = pp;
  }
  if (pt < 32) {
    float acc = w.sc0b[pt];
    #pragma unroll
    for (int c = 0; c < 32; c++) acc += s_sh[c] * w.sc0w[c*32 + pt];
    h_sh[pt] = fmaxf(acc, 0.f);
  }
  WAVE_SYNC();
  if (pt < 32) {
    float acc = w.sc1b[pt] + h_sh[pt];
    #pragma unroll
    for (int c = 0; c < 32; c++) acc += h_sh[c] * w.sc1w[c*32 + pt];
    SD[(size_t)bo*32 + pt] = acc;
  }
  if (pt == 0) { PX[bo] = s_sh[0]; PY[bo] = s_sh[1]; }
}

// ---------------------------------------------------------------------------
// fused init: present copy + weight pack (blocks 0,1) + S0 + projections.
// ---------------------------------------------------------------------------
__global__ __launch_bounds__(256)
void init_kernel(const float* __restrict__ x, const float* __restrict__ sew,
                 const float* __restrict__ seb, W w,
                 float* __restrict__ present, float* __restrict__ S0,
                 float* SD, float* P1R, float* P1A, float* P2AR,
                 float* PX, float* PY,
                 uint4* __restrict__ fragbuf, float* __restrict__ geoAs)
{
  __shared__ float sbuf[2][160];
  int tid = threadIdx.x, bid = blockIdx.x;

  // ---- A: coalesced present copy ----
  {
    int idx = bid*256 + tid;
    if (idx < NB*4*NOBJ*4) present[idx] = x[idx];
  }

  // ---- B: weight pack + scaled geo rows (blocks 0,1) ----
  if (bid < 2) {
    int t5 = bid*256 + tid;       // 0..511
    int lane = t5 & 63, kt = (t5>>6)&1, nt = (t5>>7)&1, path = t5>>8;
    const float* src = path ? w.rc1w : w.at1w;
    float sc = path ? 1.f : C2F;
    int c16p = lane & 15, qgp = lane >> 4;
    unsigned r[4];
    #pragma unroll
    for (int e2 = 0; e2 < 4; e2++){
      int k0 = kt*32 + qgp*8 + e2*2;
      unsigned lo = f2bf(src[k0*32     + nt*16 + c16p] * sc);
      unsigned hi = f2bf(src[(k0+1)*32 + nt*16 + c16p] * sc);
      r[e2] = lo | (hi << 16);
    }
    uint4 v; v.x=r[0]; v.y=r[1]; v.z=r[2]; v.w=r[3];
    fragbuf[((path*2+nt)*2+kt)*64 + lane] = v;
    if (t5 < 192) geoAs[t5] = w.at0w[64*64 + t5] * C2F;
  }

  // ---- C: S0 + projection for this block's 2 objects (wave-local) ----
  int og = tid >> 7, tl = tid & 127;
  int bo = bid*2 + og, o = bo & 127, b = bo >> 7;
  float* s_sh = sbuf[og];
  float* h_sh = s_sh + 128;
  const float* xr = x + (size_t)((b*4 + 3)*NOBJ + o)*4;
  if (tl < 32) {
    float v;
    if (tl < 4) v = xr[tl];
    else v = seb[tl] + xr[0]*sew[tl] + xr[1]*sew[32+tl]
           + xr[2]*sew[64+tl] + xr[3]*sew[96+tl];
    s_sh[tl] = v;
    S0[(size_t)bo*32 + tl] = v;
  }
  WAVE_SYNC();
  project_body(tl, bo, s_sh, h_sh, w, SD, P1R, P1A, P2AR, PX, PY);
}

// GEMM pass over one object's 128x64 bf16 swizzled tile.
#define GEMM_PASS(TBASE, BF, COUT) do {                                       \
  _Pragma("unroll")                                                           \
  for (int mt = 0; mt < 4; mt++){                                             \
    int jr = (wv2<<6) + (mt<<4) + c16;                                        \
    const char* rb = (const char*)(TBASE) + (jr<<7);                          \
    bfrag a0 = *((const bfrag*)(rb + (((qg  ) ^ (jr&7))<<4)));                \
    bfrag a1 = *((const bfrag*)(rb + (((4+qg) ^ (jr&7))<<4)));                \
    _Pragma("unroll")                                                         \
    for (int nt = 0; nt < 2; nt++){                                           \
      COUT[mt][nt] = __builtin_amdgcn_mfma_f32_16x16x32_bf16(a0, BF[nt][0], COUT[mt][nt], 0,0,0); \
      COUT[mt][nt] = __builtin_amdgcn_mfma_f32_16x16x32_bf16(a1, BF[nt][1], COUT[mt][nt], 0,0,0); \
    }                                                                         \
  }                                                                           \
} while(0)

// ---------------------------------------------------------------------------
// one rollout step.  block = (b, object-pair), 256 threads (4 waves).
// 5 cross-wave barriers only; tails + projection are wave-synchronous
// (og=0 entirely in wave 0, og=1 entirely in wave 2).
// ---------------------------------------------------------------------------
__global__ __launch_bounds__(256)
void step_kernel(const float* __restrict__ S_in,  const float* __restrict__ SD_in,
                 const float* __restrict__ P1R_in, const float* __restrict__ P1A_in,
                 const float* __restrict__ P2AR_in,
                 const float* __restrict__ PX_in,  const float* __restrict__ PY_in,
                 float* __restrict__ S_out, float* __restrict__ SD_out,
                 float* __restrict__ P1R_out, float* __restrict__ P1A_out,
                 float* __restrict__ P2AR_out,
                 float* __restrict__ PX_out, float* __restrict__ PY_out,
                 const uint4* __restrict__ fragbuf, const float* __restrict__ geoAs,
                 W w, float* __restrict__ out_roll, int tstep)
{
  __shared__ __align__(16) float smem[8192];   // EXACTLY 32 KB
  float* qb_base = smem;          // aliased into tile0 after GEMM2
  float* vb_base = smem + 512;

  int tid = threadIdx.x;
  int g   = tid >> 7;             // k-half for prep
  int lt  = tid & 127;            // j
  int w4  = tid >> 6;             // wave 0..3
  int obj = w4 >> 1;              // object for GEMM/attv/q phases
  int wv2 = w4 & 1;               // M-half within object
  int l = tid & 63, c16 = l & 15, qg = l >> 4;

  int p = blockIdx.x & 63, b = blockIdx.x >> 6;
  int i0 = 2*p;
  int bi0 = b*NOBJ + i0, bi1 = bi0 + 1;

  char* t0 = (char*)smem;
  char* t1 = (char*)smem + 16384;

  // ---- att B-fragments (pre-packed & pre-scaled; 4 x 16B loads) ----
  bfrag bfA[2][2];
  #pragma unroll
  for (int nt = 0; nt < 2; nt++)
    #pragma unroll
    for (int kt = 0; kt < 2; kt++)
      bfA[nt][kt] = *((const bfrag*)&fragbuf[(nt*2+kt)*64 + l]);

  // ---- geometry for both objects ----
  float px0 = S_in[(size_t)bi0*32 + 0], py0 = S_in[(size_t)bi0*32 + 1];
  float px1 = S_in[(size_t)bi1*32 + 0], py1 = S_in[(size_t)bi1*32 + 1];
  float px_j = PX_in[b*NOBJ + lt], py_j = PY_in[b*NOBJ + lt];
  float dx0 = px0 - px_j, dy0 = py0 - py_j;
  float dx1 = px1 - px_j, dy1 = py1 - py_j;
  float dist0 = sqrtf(dx0*dx0 + dy0*dy0 + 1e-10f);
  float dist1 = sqrtf(dx1*dx1 + dy1*dy1 + 1e-10f);

  const float2* p2p = ((const float2*)P2AR_in) + (size_t)(b*64)*NOBJ + lt;
  const float* p1a0 = P1A_in + (size_t)bi0*64;   // scaled
  const float* p1r0 = P1R_in + (size_t)bi0*64;
  const float* p1a1 = P1A_in + (size_t)bi1*64;   // scaled
  const float* p1r1 = P1R_in + (size_t)bi1*64;
  const float* gR = w.rc0w + 64*64;

  // ---- fused prep: 32 p2p loads -> acts for BOTH objects (packed f32) ----
  unsigned relpk[2][16];
  #pragma unroll
  for (int sl = 0; sl < 4; sl++){
    unsigned aw0[4], aw1[4];
    #pragma unroll
    for (int e2 = 0; e2 < 4; e2++){
      int k0 = g*32 + sl*8 + e2*2;
      float2 pa0 = p2p[(size_t)k0*NOBJ];
      float2 pa1 = p2p[(size_t)(k0+1)*NOBJ];
      f2 pA = {pa0.x, pa1.x};
      f2 pR = {pa0.y, pa1.y};
      f2 g0 = *(const f2*)&geoAs[k0];
      f2 g1 = *(const f2*)&geoAs[64+k0];
      f2 g2 = *(const f2*)&geoAs[128+k0];
      f2 h0 = *(const f2*)&gR[k0];
      f2 h1 = *(const f2*)&gR[64+k0];
      f2 h2 = *(const f2*)&gR[128+k0];
      f2 pA0v = *(const f2*)&p1a0[k0];
      f2 pR0v = *(const f2*)&p1r0[k0];
      f2 pA1v = *(const f2*)&p1a1[k0];
      f2 pR1v = *(const f2*)&p1r1[k0];
      f2 xA0 = pA0v + pA + dist0*g0 + dx0*g1 + dy0*g2;
      f2 xR0 = pR0v + pR + dist0*h0 + dx0*h1 + dy0*h2;
      f2 xA1 = pA1v + pA + dist1*g0 + dx1*g1 + dy1*g2;
      f2 xR1 = pR1v + pR + dist1*h0 + dx1*h1 + dy1*h2;
      aw0[e2] = cvt_pk_bf16(tanh4(xA0.x), tanh4(xA0.y));
      relpk[0][sl*4+e2] = cvt_pk_bf16(fmaxf(xR0.x,0.f), fmaxf(xR0.y,0.f));
      aw1[e2] = cvt_pk_bf16(tanh4(xA1.x), tanh4(xA1.y));
      relpk[1][sl*4+e2] = cvt_pk_bf16(fmaxf(xR1.x,0.f), fmaxf(xR1.y,0.f));
    }
    int s = g*4 + sl;
    unsigned off = (lt<<7) + ((s ^ (lt&7))<<4);
    uint4 pk0; pk0.x=aw0[0]; pk0.y=aw0[1]; pk0.z=aw0[2]; pk0.w=aw0[3];
    uint4 pk1; pk1.x=aw1[0]; pk1.y=aw1[1]; pk1.z=aw1[2]; pk1.w=aw1[3];
    *((uint4*)(t0 + off)) = pk0;
    *((uint4*)(t1 + off)) = pk1;
  }
  __syncthreads();                               // [1] tiles ready (cross-wave)

  // ================= attention GEMMs (waves 0,1: obj0 | 2,3: obj1) ========
  const char* mytile = (const char*)smem + (obj<<14);
  f4t cA[4][2];
  #pragma unroll
  for (int mt = 0; mt < 4; mt++)
    #pragma unroll
    for (int nt = 0; nt < 2; nt++) cA[mt][nt] = (f4t){0.f,0.f,0.f,0.f};
  GEMM_PASS(mytile, bfA, cA);
  __syncthreads();                               // [2] tile reads done

  // ---- store rel tiles (overwrite) + attv epilogue (reg-only) ----
  #pragma unroll
  for (int sl = 0; sl < 4; sl++){
    int s = g*4 + sl;
    unsigned off = (lt<<7) + ((s ^ (lt&7))<<4);
    uint4 pk0; pk0.x=relpk[0][sl*4]; pk0.y=relpk[0][sl*4+1];
               pk0.z=relpk[0][sl*4+2]; pk0.w=relpk[0][sl*4+3];
    uint4 pk1; pk1.x=relpk[1][sl*4]; pk1.y=relpk[1][sl*4+1];
               pk1.z=relpk[1][sl*4+2]; pk1.w=relpk[1][sl*4+3];
    *((uint4*)(t0 + off)) = pk0;
    *((uint4*)(t1 + off)) = pk1;
  }

  int i_self = i0 + obj;
  float attv[16];
  {
    float bA0 = w.at1b[c16] * C2F, bA1 = w.at1b[16 + c16] * C2F;
    float w20 = w.at2w[c16], w21 = w.at2w[16 + c16];
    float a2b = w.at2b[0];
    #pragma unroll
    for (int mt = 0; mt < 4; mt++)
      #pragma unroll
      for (int reg = 0; reg < 4; reg++) {
        float s = tanh4(cA[mt][0][reg] + bA0) * w20
                + tanh4(cA[mt][1][reg] + bA1) * w21;
        s += __shfl_xor(s, 1); s += __shfl_xor(s, 2);
        s += __shfl_xor(s, 4); s += __shfl_xor(s, 8);
        int jj = wv2*64 + mt*16 + qg*4 + reg;
        attv[mt*4 + reg] = (jj == i_self) ? 0.f : __expf(s + a2b);
      }
  }

  // ---- rel B-fragments (loaded late) ----
  bfrag bfR[2][2];
  #pragma unroll
  for (int nt = 0; nt < 2; nt++)
    #pragma unroll
    for (int kt = 0; kt < 2; kt++)
      bfR[nt][kt] = *((const bfrag*)&fragbuf[(4 + nt*2+kt)*64 + l]);
  __syncthreads();                               // [3] rel tiles ready

  // ================= relation GEMMs =================
  f4t cR[4][2];
  #pragma unroll
  for (int mt = 0; mt < 4; mt++)
    #pragma unroll
    for (int nt = 0; nt < 2; nt++) cR[mt][nt] = (f4t){0.f,0.f,0.f,0.f};
  GEMM_PASS(mytile, bfR, cR);

  // epilogue: q = sum_j att_j * relu(r2pre_j), A = sum_j att_j  (regs only)
  float q0 = 0.f, q1 = 0.f, Ap = 0.f;
  {
    float bR0 = w.rc1b[c16], bR1 = w.rc1b[16 + c16];
    #pragma unroll
    for (int mt = 0; mt < 4; mt++)
      #pragma unroll
      for (int reg = 0; reg < 4; reg++) {
        float av = attv[mt*4 + reg]; Ap += av;
        q0 += av * fmaxf(cR[mt][0][reg] + bR0, 0.f);
        q1 += av * fmaxf(cR[mt][1][reg] + bR1, 0.f);
      }
    q0 += __shfl_xor(q0, 16); q0 += __shfl_xor(q0, 32);
    q1 += __shfl_xor(q1, 16); q1 += __shfl_xor(q1, 32);
    Ap += __shfl_xor(Ap, 16); Ap += __shfl_xor(Ap, 32);
  }
  __syncthreads();                               // [4] GEMM2 reads done
  {
    float* qb = qb_base + obj*66;
    if (l < 16) { qb[wv2*33 + l] = q0; qb[wv2*33 + 16 + l] = q1; }
    if (l == 0) qb[wv2*33 + 32] = Ap;
  }
  __syncthreads();                               // [5] qb visible to tails

  // ---- per-object tails: WAVE-SYNCHRONOUS (og=0 wave0, og=1 wave2) ----
  int og = tid >> 7, tl = tid & 127;
  int bio = bi0 + og;
  float* qbo  = qb_base + og*66;
  float* v0_sh = vb_base + og*160;
  float* v1_sh = v0_sh + 32;
  float* v2_sh = v0_sh + 64;
  float* snew_sh = v0_sh + 96;
  float* h_sh = v0_sh + 128;
  int outc = tl & 31, half = (tl >> 5) & 1;

  if (tl < 64) {
    if (tl < 32) v2_sh[tl] = qbo[tl] + qbo[33 + tl];   // q combined
    WAVE_SYNC();
    {                                   // dyn = SD + q@rc2w + A*rc2b + q
      float acc = 0.f;
      #pragma unroll
      for (int k = 0; k < 16; k++) acc += v2_sh[half*16+k] * w.rc2w[(half*16+k)*32 + outc];
      acc += __shfl_xor(acc, 32);
      if (!half) {
        float A = qbo[32] + qbo[65];
        v0_sh[outc] = SD_in[(size_t)bio*32 + outc] + A * w.rc2b[outc] + v2_sh[outc] + acc;
      }
    }
    WAVE_SYNC();
    {                                   // aff1
      float acc = 0.f;
      #pragma unroll
      for (int k = 0; k < 16; k++) acc += v0_sh[half*16+k] * w.af0w[(half*16+k)*32 + outc];
      acc += __shfl_xor(acc, 32);
      if (!half) v1_sh[outc] = fast_tanh(acc + w.af0b[outc]);
    }
    WAVE_SYNC();
    {                                   // aff2
      float acc = 0.f;
      #pragma unroll
      for (int k = 0; k < 16; k++) acc += v1_sh[half*16+k] * w.af1w[(half*16+k)*32 + outc];
      acc += __shfl_xor(acc, 32);
      if (!half) v2_sh[outc] = fast_tanh(acc + w.af1b[outc]) + v1_sh[outc];
    }
    WAVE_SYNC();
    {                                   // aff3
      float acc = 0.f;
      #pragma unroll
      for (int k = 0; k < 16; k++) acc += v2_sh[half*16+k] * w.af2w[(half*16+k)*32 + outc];
      acc += __shfl_xor(acc, 32);
      if (!half) v0_sh[outc] = acc + w.af2b[outc];
    }
    WAVE_SYNC();
    {                                   // out1 = tanh([aff3,s]@o0+b), K=64
      float acc = 0.f;
      #pragma unroll
      for (int k = 0; k < 32; k++) {
        float src = half ? S_in[(size_t)bio*32 + k] : v0_sh[k];
        acc += src * w.o0w[(half*32+k)*32 + outc];
      }
      acc += __shfl_xor(acc, 32);
      if (!half) v1_sh[outc] = fast_tanh(acc + w.o0b[outc]);
    }
    WAVE_SYNC();
    {                                   // res = out1@o1 + b + out1 (+s[:2])
      float acc = 0.f;
      #pragma unroll
      for (int k = 0; k < 16; k++) acc += v1_sh[half*16+k] * w.o1w[(half*16+k)*32 + outc];
      acc += __shfl_xor(acc, 32);
      if (!half) {
        acc += w.o1b[outc] + v1_sh[outc];
        if (outc < 2) acc += S_in[(size_t)bio*32 + outc];
        snew_sh[outc] = acc;
        S_out[(size_t)bio*32 + outc] = acc;
        if (outc < 4)
          out_roll[(size_t)((b*NROLL + tstep)*NOBJ + (i0 + og))*4 + outc] = acc;
      }
    }
    WAVE_SYNC();
    // ---- fused projections of the NEW states (wave-local) ----
    project_body(tl, bio, snew_sh, h_sh, w,
                 SD_out, P1R_out, P1A_out, P2AR_out, PX_out, PY_out);
  }
}

// ---------------------------------------------------------------------------
extern "C" void kernel_launch(void* const* d_in, const int* in_sizes, int n_in,
                              void* d_out, int out_size, void* d_ws, size_t ws_size,
                              hipStream_t stream)
{
  const float* x    = (const float*)d_in[0];
  const float* sew  = (const float*)d_in[1];
  const float* seb  = (const float*)d_in[2];
  W w;
  w.sc0w=(const float*)d_in[3];  w.sc0b=(const float*)d_in[4];
  w.sc1w=(const float*)d_in[5];  w.sc1b=(const float*)d_in[6];
  w.rc0w=(const float*)d_in[7];  w.rc0b=(const float*)d_in[8];
  w.rc1w=(const float*)d_in[9];  w.rc1b=(const float*)d_in[10];
  w.rc2w=(const float*)d_in[11]; w.rc2b=(const float*)d_in[12];
  w.at0w=(const float*)d_in[13]; w.at0b=(const float*)d_in[14];
  w.at1w=(const float*)d_in[15]; w.at1b=(const float*)d_in[16];
  w.at2w=(const float*)d_in[17]; w.at2b=(const float*)d_in[18];
  w.af0w=(const float*)d_in[19]; w.af0b=(const float*)d_in[20];
  w.af1w=(const float*)d_in[21]; w.af1b=(const float*)d_in[22];
  w.af2w=(const float*)d_in[23]; w.af2b=(const float*)d_in[24];
  w.o0w =(const float*)d_in[25]; w.o0b =(const float*)d_in[26];
  w.o1w =(const float*)d_in[27]; w.o1b =(const float*)d_in[28];

  float* out = (float*)d_out;
  float* out_roll    = out;                              // (16,8,128,4)
  float* out_present = out + NB*NROLL*NOBJ*4;            // (16,4,128,4)

  float* ws = (float*)d_ws;
  size_t off = 0;
  auto alloc = [&](size_t n){ float* p = ws + off; off += n; return p; };
  float* S[2]    = { alloc(NB*NOBJ*32),   alloc(NB*NOBJ*32) };
  float* SD[2]   = { alloc(NB*NOBJ*32),   alloc(NB*NOBJ*32) };
  float* P1R[2]  = { alloc(NB*NOBJ*64),   alloc(NB*NOBJ*64) };
  float* P1A[2]  = { alloc(NB*NOBJ*64),   alloc(NB*NOBJ*64) };
  float* P2AR[2] = { alloc(NB*64*NOBJ*2), alloc(NB*64*NOBJ*2) };
  float* PX[2]   = { alloc(NB*NOBJ),      alloc(NB*NOBJ) };
  float* PY[2]   = { alloc(NB*NOBJ),      alloc(NB*NOBJ) };
  uint4* fragbuf = (uint4*)alloc(512 * 4);               // 8 KB packed B-frags
  float* geoAs   = alloc(192);                           // scaled att geo rows
  (void)ws_size; (void)in_sizes; (void)n_in; (void)out_size;

  hipLaunchKernelGGL(init_kernel, dim3(NB*NOBJ/2), dim3(256), 0, stream,
                     x, sew, seb, w, out_present, S[0],
                     SD[0], P1R[0], P1A[0], P2AR[0], PX[0], PY[0],
                     fragbuf, geoAs);

  for (int t = 0; t < NROLL; t++) {
    int a = t & 1, oo = 1 - a;
    hipLaunchKernelGGL(step_kernel, dim3(NB*NOBJ/2), dim3(256), 0, stream,
                       S[a], SD[a], P1R[a], P1A[a], P2AR[a], PX[a], PY[a],
                       S[oo], SD[oo], P1R[oo], P1A[oo], P2AR[oo], PX[oo], PY[oo],
                       fragbuf, geoAs, w, out_roll, t);
  }
}